// Round 14
// baseline (568.383 us; speedup 1.0000x reference)
//
#include <hip/hip_runtime.h>

#define N_NODES 50000
#define MPAD 50176            // 784*64, node-buffer row padding for GEMM staging
#define N_EDGES 800000
#define DIM 256
#define N_GRAPHS 500
#define N_OUT 10
#define BN_EPS 1e-5f
#define SCAN_BS 1024
#define KSPLIT 4
#define SORT_CAP 96           // max degree handled by sort (Poisson(16): P(deg>96) ~ 0)

typedef unsigned int u32;
typedef short bf16x8 __attribute__((ext_vector_type(8)));
typedef unsigned short us8 __attribute__((ext_vector_type(8)));
typedef float f32x4 __attribute__((ext_vector_type(4)));

typedef __attribute__((address_space(1))) const unsigned int gas_u32;
typedef __attribute__((address_space(3))) unsigned int las_u32;

__device__ inline void g2l16(const void* g, void* l) {
    // async global->LDS, 16 bytes per lane; LDS dest = wave-uniform base + lane*16
    __builtin_amdgcn_global_load_lds((gas_u32*)g, (las_u32*)l, 16, 0, 0);
}

__device__ inline float b2f(unsigned short u) {
    union { u32 i; float f; } c; c.i = ((u32)u) << 16; return c.f;
}
__device__ inline unsigned short f2b(float f) {   // round-to-nearest-even
    u32 x = __builtin_bit_cast(u32, f);
    return (unsigned short)((x + 0x7FFFu + ((x >> 16) & 1u)) >> 16);
}

// swizzled byte address into the 64x256-bf16 mid LDS tile (row stride 512B = 32 slots):
// slot ^= row&31 is bijective per row and de-conflicts stride-512B column reads.
__device__ inline int mid_addr(int row, int col) {
    return row * 512 + ((((col >> 3) ^ (row & 31)) << 4) | ((col & 7) << 1));
}

// ---------------- CSR build ----------------
__global__ void zero_i(int* __restrict__ p, int n) {
    int i = blockIdx.x * blockDim.x + threadIdx.x;
    if (i < n) p[i] = 0;
}
__global__ void hist_dst(const int* __restrict__ dst, int* __restrict__ deg) {
    int e = blockIdx.x * blockDim.x + threadIdx.x;
    if (e < N_EDGES) atomicAdd(&deg[dst[e]], 1);
}
__global__ void scan_phase1(const int* __restrict__ deg, int* __restrict__ rowptr,
                            int* __restrict__ bsum, int n) {
    __shared__ int sh[SCAN_BS];
    int i = blockIdx.x * SCAN_BS + threadIdx.x;
    int v = (i < n) ? deg[i] : 0;
    sh[threadIdx.x] = v;
    __syncthreads();
    for (int off = 1; off < SCAN_BS; off <<= 1) {
        int t = (threadIdx.x >= off) ? sh[threadIdx.x - off] : 0;
        __syncthreads();
        sh[threadIdx.x] += t;
        __syncthreads();
    }
    if (i < n) rowptr[i] = sh[threadIdx.x] - v;
    if (threadIdx.x == SCAN_BS - 1) bsum[blockIdx.x] = sh[threadIdx.x];
}
__global__ void scan_phase2(int* __restrict__ bsum, int nb) {
    if (threadIdx.x == 0 && blockIdx.x == 0) {
        int run = 0;
        for (int b = 0; b < nb; b++) { int v = bsum[b]; bsum[b] = run; run += v; }
    }
}
__global__ void scan_phase3(int* __restrict__ rowptr, int* __restrict__ cursor,
                            const int* __restrict__ bsum, int n) {
    int i = blockIdx.x * SCAN_BS + threadIdx.x;
    if (i < n) {
        int v = rowptr[i] + bsum[blockIdx.x];
        rowptr[i] = v;
        cursor[i] = v;
    }
    if (i == 0) rowptr[n] = N_EDGES;
}
__global__ void fill_csr(const int* __restrict__ src, const int* __restrict__ dst,
                         int* __restrict__ cursor, int* __restrict__ col) {
    int e = blockIdx.x * blockDim.x + threadIdx.x;
    if (e < N_EDGES) {
        int p = atomicAdd(&cursor[dst[e]], 1);
        col[p] = src[e];
    }
}
// canonicalize neighbor order (atomic fill order is nondeterministic -> f32 sum order
// would vary call-to-call; harness requires identical output every call).
__global__ void sort_csr(const int* __restrict__ rowptr, int* __restrict__ col) {
    __shared__ int buf[4][SORT_CAP];
    int node = blockIdx.x * 4 + (threadIdx.x >> 6);
    if (node >= N_NODES) return;
    int lane = threadIdx.x & 63;
    int w = threadIdx.x >> 6;
    int s = rowptr[node], e = rowptr[node + 1];
    int L = e - s;
    if (L <= 1 || L > SORT_CAP) return;
    for (int i = lane; i < L; i += 64) buf[w][i] = col[s + i];
    asm volatile("s_waitcnt lgkmcnt(0) vmcnt(0)" ::: "memory");
    for (int pass = 0; pass < L; pass++) {
        int base = 2 * lane + (pass & 1);
        if (base + 1 < L) {
            int a = buf[w][base], b = buf[w][base + 1];
            if (a > b) { buf[w][base] = b; buf[w][base + 1] = a; }
        }
        asm volatile("s_waitcnt lgkmcnt(0)" ::: "memory");
    }
    for (int i = lane; i < L; i += 64) col[s + i] = buf[w][i];
}
__global__ void graph_starts(const int* __restrict__ batch, int* __restrict__ gstart) {
    int g = blockIdx.x * blockDim.x + threadIdx.x;
    if (g > N_GRAPHS) return;
    if (g == N_GRAPHS) { gstart[g] = N_NODES; return; }
    int lo = 0, hi = N_NODES;
    while (lo < hi) { int mid = (lo + hi) >> 1; if (batch[mid] < g) lo = mid + 1; else hi = mid; }
    gstart[g] = lo;
}

// ---------------- conversions ----------------
__global__ void conv_x(const float4* __restrict__ in, ushort4* __restrict__ out, int n4) {
    int i = blockIdx.x * blockDim.x + threadIdx.x;
    if (i < n4) {
        float4 v = in[i];
        ushort4 o; o.x = f2b(v.x); o.y = f2b(v.y); o.z = f2b(v.z); o.w = f2b(v.w);
        out[i] = o;
    }
}
// Wt[mat][n][k] = bf16(W[mat][k][n])
__global__ void conv_wt4(const float* __restrict__ W0, const float* __restrict__ W1,
                         const float* __restrict__ W2, const float* __restrict__ W3,
                         unsigned short* __restrict__ Wt) {
    int mat = blockIdx.y;
    const float* W = (mat == 0) ? W0 : (mat == 1) ? W1 : (mat == 2) ? W2 : W3;
    int n = blockIdx.x;
    int k = threadIdx.x;
    Wt[((size_t)mat << 16) + (size_t)n * 256 + k] = f2b(W[(size_t)k * 256 + n]);
}
__global__ void make_ss(const float* __restrict__ bias, const float* __restrict__ gamma,
                        const float* __restrict__ beta, const float* __restrict__ mean,
                        const float* __restrict__ var, float* __restrict__ scale,
                        float* __restrict__ shift) {
    int i = threadIdx.x;
    float s = gamma[i] * rsqrtf(var[i] + BN_EPS);
    scale[i] = s;
    shift[i] = (bias[i] - mean[i]) * s + beta[i];
}

// ---------------- pass-split gather: out[i] = feat[i] + sum_{j in N(i)} feat[j] ----------------
// grid (nodes/4, 8 passes); block 256 = 4 waves; wave = 1 node.
// Pass p reads only a 64 B slice of each row -> 3.2 MB working set, L2-resident per XCD.
// Wave: 16 edge-groups x 4 lanes x 16 B -> 16 row-streams in flight per load issue.
// Deterministic: col is sorted (sort_csr), group assignment and reduce tree are fixed.
__global__ void gather_ps(const unsigned short* __restrict__ feat,
                          const int* __restrict__ col,
                          const int* __restrict__ rowptr,
                          unsigned short* __restrict__ out) {
    int node = blockIdx.x * 4 + (threadIdx.x >> 6);
    if (node >= N_NODES) return;
    int pass = blockIdx.y;
    int lane = threadIdx.x & 63;
    int eg = lane >> 2;               // edge group 0..15
    int dbase = pass * 32 + (lane & 3) * 8;   // element offset within row

    float acc[8];
    #pragma unroll
    for (int j = 0; j < 8; j++) acc[j] = 0.f;
    if (eg == 0) {    // fold own row into group 0's partial (overlaps with edge loads)
        us8 own = *reinterpret_cast<const us8*>(&feat[(size_t)node * DIM + dbase]);
        #pragma unroll
        for (int j = 0; j < 8; j++) acc[j] = b2f((unsigned short)own[j]);
    }
    int s = rowptr[node], e = rowptr[node + 1];
    for (int i = s + eg; i < e; i += 16) {
        int src = col[i];
        us8 v = *reinterpret_cast<const us8*>(&feat[(size_t)src * DIM + dbase]);
        #pragma unroll
        for (int j = 0; j < 8; j++) acc[j] += b2f((unsigned short)v[j]);
    }
    // reduce across the 16 edge groups (lanes with equal lane&3)
    #pragma unroll
    for (int m = 4; m <= 32; m <<= 1)
        #pragma unroll
        for (int j = 0; j < 8; j++) acc[j] += __shfl_xor(acc[j], m, 64);
    if (eg == 0) {
        us8 o;
        #pragma unroll
        for (int j = 0; j < 8; j++) o[j] = (short)f2b(acc[j]);
        *reinterpret_cast<us8*>(&out[(size_t)node * DIM + dbase]) = o;
    }
}

// ---------------- fused GIN MLP:  H = relu(relu(bn(A@W1)) @ W2 + b2), all in one block pass ------
// 256 threads, 64-row tile, 4 waves as 1M x 4N (wave 64x64), BK=32, K=256.
// Conservative sync: __syncthreads() full drains only (R13-proven).
__global__ __launch_bounds__(256, 2)
void fused_mlp(const unsigned short* __restrict__ A,
               const unsigned short* __restrict__ W1t,   // [256][256], W1t[n][k]
               const unsigned short* __restrict__ W2t,   // [256][256], W2t[n][k]
               const float* __restrict__ scale1,
               const float* __restrict__ shift1,
               const float* __restrict__ shift2,         // b2
               unsigned short* __restrict__ H, int M) {
    __shared__ __align__(16) unsigned short Asb[2][64 * 32];    // 2 x 4 KB
    __shared__ __align__(16) unsigned short Bsb[2][256 * 32];   // 2 x 16 KB
    __shared__ __align__(16) unsigned short midb[64 * 256];     // 32 KB, swizzled

    int t = threadIdx.x;
    int wave = t >> 6, lane = t & 63;
    int m0 = blockIdx.x * 64;
    int wc = wave * 64;
    int rsel = lane & 15;
    int ksel = (lane >> 4) * 8;
    int cr = lane >> 4;

    float s1[4], sh1[4], sh2[4];
    #pragma unroll
    for (int n = 0; n < 4; n++) {
        int colg = wc + n * 16 + rsel;
        s1[n]  = scale1[colg];
        sh1[n] = shift1[colg];
        sh2[n] = shift2[colg];
    }

    int cb = (t & 3) * 16;
    const char* Ab  = (const char*)A   + (size_t)(m0 + (t >> 2)) * 512 + cb;
    const char* B1b = (const char*)W1t + (size_t)(t >> 2) * 512 + cb;
    const char* B2b = (const char*)W2t + (size_t)(t >> 2) * 512 + cb;

    f32x4 acc[4][4];
    #pragma unroll
    for (int m = 0; m < 4; m++)
        #pragma unroll
        for (int n = 0; n < 4; n++)
            acc[m][n] = (f32x4){0.f, 0.f, 0.f, 0.f};

    // prologue: stage phase-1 tiles 0,1
    #pragma unroll
    for (int p = 0; p < 2; p++) {
        size_t ko = (size_t)p * 64;
        g2l16(Ab + ko, (char*)Asb[p] + (size_t)t * 16);
        #pragma unroll
        for (int i = 0; i < 4; i++)
            g2l16(B1b + (size_t)i * 32768 + ko, (char*)Bsb[p] + (size_t)(i * 256 + t) * 16);
    }

    // ---- phase 1: acc = A @ W1 ----
    #pragma unroll
    for (int ks = 0; ks < 8; ks++) {
        const int cur = ks & 1;
        __syncthreads();   // tile ks staged (full vm+lgkm drain)

        const unsigned short* As = Asb[cur];
        const unsigned short* Bs = Bsb[cur];
        bf16x8 af[4], bfr[4];
        #pragma unroll
        for (int m = 0; m < 4; m++)
            af[m] = *(const bf16x8*)&As[(size_t)(m * 16 + rsel) * 32 + ksel];
        #pragma unroll
        for (int n = 0; n < 4; n++)
            bfr[n] = *(const bf16x8*)&Bs[(size_t)(wc + n * 16 + rsel) * 32 + ksel];
        #pragma unroll
        for (int m = 0; m < 4; m++)
            #pragma unroll
            for (int n = 0; n < 4; n++)
                acc[m][n] = __builtin_amdgcn_mfma_f32_16x16x32_bf16(af[m], bfr[n], acc[m][n], 0, 0, 0);

        __syncthreads();   // all waves done reading buf[cur]
        if (ks + 2 < 8) {            // restage buf[cur] with phase-1 tile ks+2
            size_t ko = (size_t)(ks + 2) * 64;
            g2l16(Ab + ko, (char*)Asb[cur] + (size_t)t * 16);
            #pragma unroll
            for (int i = 0; i < 4; i++)
                g2l16(B1b + (size_t)i * 32768 + ko, (char*)Bsb[cur] + (size_t)(i * 256 + t) * 16);
        } else if (ks == 6) {        // Bsb[0] free -> prefetch W2 tile 0
            #pragma unroll
            for (int i = 0; i < 4; i++)
                g2l16(B2b + (size_t)i * 32768, (char*)Bsb[0] + (size_t)(i * 256 + t) * 16);
        } else {                     // ks == 7: Bsb[1] free -> prefetch W2 tile 1
            #pragma unroll
            for (int i = 0; i < 4; i++)
                g2l16(B2b + (size_t)i * 32768 + 64, (char*)Bsb[1] + (size_t)(i * 256 + t) * 16);
        }
    }

    // ---- epilogue 1: mid = relu(acc*scale1 + shift1) -> bf16 -> swizzled LDS; reset acc ----
    #pragma unroll
    for (int n = 0; n < 4; n++) {
        int colg = wc + n * 16 + rsel;
        #pragma unroll
        for (int m = 0; m < 4; m++) {
            int rowb = m * 16 + cr * 4;
            #pragma unroll
            for (int r = 0; r < 4; r++) {
                float v = fmaxf(acc[m][n][r] * s1[n] + sh1[n], 0.f);
                *(unsigned short*)((char*)midb + mid_addr(rowb + r, colg)) = f2b(v);
                acc[m][n][r] = 0.f;
            }
        }
    }

    // ---- phase 2: acc = mid @ W2 ----
    #pragma unroll
    for (int ks = 0; ks < 8; ks++) {
        const int cur = ks & 1;
        __syncthreads();   // W2 tile ks staged; (first iter) midb writes visible

        const unsigned short* Bs = Bsb[cur];
        bf16x8 af[4], bfr[4];
        #pragma unroll
        for (int m = 0; m < 4; m++)
            af[m] = *(const bf16x8*)((const char*)midb + mid_addr(m * 16 + rsel, ks * 32 + ksel));
        #pragma unroll
        for (int n = 0; n < 4; n++)
            bfr[n] = *(const bf16x8*)&Bs[(size_t)(wc + n * 16 + rsel) * 32 + ksel];
        #pragma unroll
        for (int m = 0; m < 4; m++)
            #pragma unroll
            for (int n = 0; n < 4; n++)
                acc[m][n] = __builtin_amdgcn_mfma_f32_16x16x32_bf16(af[m], bfr[n], acc[m][n], 0, 0, 0);

        __syncthreads();   // all waves done reading buf[cur]
        if (ks + 2 < 8) {            // restage buf[cur] with W2 tile ks+2
            size_t ko = (size_t)(ks + 2) * 64;
            #pragma unroll
            for (int i = 0; i < 4; i++)
                g2l16(B2b + (size_t)i * 32768 + ko, (char*)Bsb[cur] + (size_t)(i * 256 + t) * 16);
        }
    }

    // ---- epilogue 2: H = relu(acc + b2) ----
    #pragma unroll
    for (int n = 0; n < 4; n++) {
        int colg = wc + n * 16 + rsel;
        #pragma unroll
        for (int m = 0; m < 4; m++) {
            int rowb = m0 + m * 16 + cr * 4;
            #pragma unroll
            for (int r = 0; r < 4; r++) {
                int row = rowb + r;
                if (row < M) {
                    float v = fmaxf(acc[m][n][r] + sh2[n], 0.f);
                    H[(size_t)row * 256 + colg] = f2b(v);
                }
            }
        }
    }
}

// ---------------- pooling (bf16 in, f32 out, concatenated [g][512]) ----------------
__global__ void pool_seg(const unsigned short* __restrict__ h1,
                         const unsigned short* __restrict__ h2,
                         const int* __restrict__ gstart,
                         float* __restrict__ pcat) {
    int g = blockIdx.x;
    int t = threadIdx.x;
    int s = gstart[g], e = gstart[g + 1];
    float a1 = 0.f, a2 = 0.f;
    for (int n = s; n < e; n++) {
        a1 += b2f(h1[(size_t)n * DIM + t]);
        a2 += b2f(h2[(size_t)n * DIM + t]);
    }
    pcat[(size_t)g * 512 + t]       = a1;
    pcat[(size_t)g * 512 + 256 + t] = a2;
}

// ---------------- head stage 1 (split-K): Hpart[z][500][768] = pcat[:, z*128:(z+1)*128] @ W1-slice ----
__global__ void head1(const float* __restrict__ A,    // [500][512]
                      const float* __restrict__ W1,   // [512][768]
                      float* __restrict__ Hpart) {    // [KSPLIT][500][768]
    __shared__ float As[16][65];
    __shared__ float Bs[16][65];
    int t = threadIdx.x;
    int m0 = blockIdx.y * 64;
    int n0 = blockIdx.x * 64;
    int kz = blockIdx.z * (512 / KSPLIT);
    int tx = t & 15, ty = t >> 4;
    float acc[4][4] = {};
    for (int k0 = kz; k0 < kz + 512 / KSPLIT; k0 += 16) {
        #pragma unroll
        for (int i = 0; i < 4; i++) {
            int r = (t >> 4) + i * 16;
            int k = t & 15;
            int gr = m0 + r;
            As[k][r] = (gr < N_GRAPHS) ? A[(size_t)gr * 512 + k0 + k] : 0.f;
        }
        #pragma unroll
        for (int i = 0; i < 4; i++) {
            int k = (t >> 6) + i * 4;
            int n = t & 63;
            Bs[k][n] = W1[(size_t)(k0 + k) * 768 + n0 + n];
        }
        __syncthreads();
        #pragma unroll
        for (int k = 0; k < 16; k++) {
            float a[4], b[4];
            #pragma unroll
            for (int i = 0; i < 4; i++) a[i] = As[k][ty * 4 + i];
            #pragma unroll
            for (int j = 0; j < 4; j++) b[j] = Bs[k][tx * 4 + j];
            #pragma unroll
            for (int i = 0; i < 4; i++)
                #pragma unroll
                for (int j = 0; j < 4; j++)
                    acc[i][j] += a[i] * b[j];
        }
        __syncthreads();
    }
    float* Hz = Hpart + (size_t)blockIdx.z * N_GRAPHS * 768;
    #pragma unroll
    for (int i = 0; i < 4; i++) {
        int gm = m0 + ty * 4 + i;
        if (gm >= N_GRAPHS) continue;
        #pragma unroll
        for (int j = 0; j < 4; j++) {
            int gn = n0 + tx * 4 + j;
            Hz[(size_t)gm * 768 + gn] = acc[i][j];
        }
    }
}

// ---------------- head stage 2: sum partials + bias + relu, GEMV, log_softmax ----------------
__global__ void head2(const float* __restrict__ Hpart, const float* __restrict__ b1,
                      const float* __restrict__ W2, const float* __restrict__ b2,
                      float* __restrict__ out) {
    int g = blockIdx.x;
    int lane = threadIdx.x;   // 64
    float part[N_OUT];
    #pragma unroll
    for (int o = 0; o < N_OUT; o++) part[o] = 0.f;
    for (int k = lane; k < 768; k += 64) {
        float hv = b1[k];
        #pragma unroll
        for (int z = 0; z < KSPLIT; z++)
            hv += Hpart[((size_t)z * N_GRAPHS + g) * 768 + k];
        hv = fmaxf(hv, 0.f);
        #pragma unroll
        for (int o = 0; o < N_OUT; o++) part[o] += hv * W2[(size_t)k * N_OUT + o];
    }
    #pragma unroll
    for (int o = 0; o < N_OUT; o++) {
        #pragma unroll
        for (int off = 32; off > 0; off >>= 1)
            part[o] += __shfl_down(part[o], off, 64);
    }
    if (lane == 0) {
        float logits[N_OUT];
        float mx = -1e30f;
        #pragma unroll
        for (int o = 0; o < N_OUT; o++) { logits[o] = part[o] + b2[o]; mx = fmaxf(mx, logits[o]); }
        float ssum = 0.f;
        #pragma unroll
        for (int o = 0; o < N_OUT; o++) ssum += expf(logits[o] - mx);
        float lse = logf(ssum);
        #pragma unroll
        for (int o = 0; o < N_OUT; o++)
            out[(size_t)g * N_OUT + o] = logits[o] - mx - lse;
    }
}

extern "C" void kernel_launch(void* const* d_in, const int* in_sizes, int n_in,
                              void* d_out, int out_size, void* d_ws, size_t ws_size,
                              hipStream_t stream) {
    const float* x     = (const float*)d_in[0];
    const int*   ei    = (const int*)d_in[1];
    const int*   batch = (const int*)d_in[2];
    const float* W1a = (const float*)d_in[3];
    const float* b1a = (const float*)d_in[4];
    const float* g1a = (const float*)d_in[5];
    const float* be1a= (const float*)d_in[6];
    const float* m1a = (const float*)d_in[7];
    const float* v1a = (const float*)d_in[8];
    const float* W2a = (const float*)d_in[9];
    const float* b2a = (const float*)d_in[10];
    const float* W1b = (const float*)d_in[11];
    const float* b1b = (const float*)d_in[12];
    const float* g1b = (const float*)d_in[13];
    const float* be1b= (const float*)d_in[14];
    const float* m1b = (const float*)d_in[15];
    const float* v1b = (const float*)d_in[16];
    const float* W2b = (const float*)d_in[17];
    const float* b2b = (const float*)d_in[18];
    const float* lin1_W = (const float*)d_in[19];
    const float* lin1_b = (const float*)d_in[20];
    const float* lin2_W = (const float*)d_in[21];
    const float* lin2_b = (const float*)d_in[22];

    const size_t NBUF = (size_t)MPAD * DIM;
    char* ws = (char*)d_ws;
    unsigned short* agg  = (unsigned short*)ws;            ws += NBUF * 2;
    unsigned short* h1   = (unsigned short*)ws;            ws += NBUF * 2;
    unsigned short* h2   = (unsigned short*)ws;            ws += NBUF * 2;
    unsigned short* x_bf = (unsigned short*)ws;            ws += (size_t)N_NODES * DIM * 2;
    unsigned short* Wt   = (unsigned short*)ws;            ws += 4 * 65536 * 2;
    float* ss    = (float*)ws;                             ws += 4 * 256 * 4;   // 2x(scale,shift)
    float* pcat  = (float*)ws;                             ws += (size_t)N_GRAPHS * 512 * 4;
    float* Hpart = (float*)ws;                             ws += (size_t)KSPLIT * N_GRAPHS * 768 * 4;
    int* deg     = (int*)ws;                               ws += (size_t)N_NODES * 4;
    int* cursor  = (int*)ws;                               ws += (size_t)N_NODES * 4;
    int* rowptr  = (int*)ws;                               ws += (size_t)(N_NODES + 1) * 4;
    int* bsum    = (int*)ws;                               ws += 64 * 4;
    int* col     = (int*)ws;                               ws += (size_t)N_EDGES * 4;
    int* gstart  = (int*)ws;

    const int* srcE = ei;
    const int* dstE = ei + N_EDGES;

    const int nscan = (N_NODES + SCAN_BS - 1) / SCAN_BS;

    // ---- CSR build (by dst), shared by both layers; sorted for determinism ----
    zero_i<<<(N_NODES + 255) / 256, 256, 0, stream>>>(deg, N_NODES);
    hist_dst<<<(N_EDGES + 255) / 256, 256, 0, stream>>>(dstE, deg);
    scan_phase1<<<nscan, SCAN_BS, 0, stream>>>(deg, rowptr, bsum, N_NODES);
    scan_phase2<<<1, 64, 0, stream>>>(bsum, nscan);
    scan_phase3<<<nscan, SCAN_BS, 0, stream>>>(rowptr, cursor, bsum, N_NODES);
    fill_csr<<<(N_EDGES + 255) / 256, 256, 0, stream>>>(srcE, dstE, cursor, col);
    sort_csr<<<(N_NODES + 3) / 4, 256, 0, stream>>>(rowptr, col);
    graph_starts<<<2, 256, 0, stream>>>(batch, gstart);

    // ---- precompute ----
    conv_x<<<(N_NODES * DIM / 4 + 255) / 256, 256, 0, stream>>>(
        (const float4*)x, (ushort4*)x_bf, N_NODES * DIM / 4);
    dim3 wt_grid(256, 4);
    conv_wt4<<<wt_grid, 256, 0, stream>>>(W1a, W2a, W1b, W2b, Wt);
    make_ss<<<1, 256, 0, stream>>>(b1a, g1a, be1a, m1a, v1a, ss + 0 * 512, ss + 0 * 512 + 256);
    make_ss<<<1, 256, 0, stream>>>(b1b, g1b, be1b, m1b, v1b, ss + 1 * 512, ss + 1 * 512 + 256);

    dim3 ggrid((N_NODES + 3) / 4, 8);

    // ---- layer 1 ----
    gather_ps<<<ggrid, 256, 0, stream>>>(x_bf, col, rowptr, agg);
    fused_mlp<<<MPAD / 64, 256, 0, stream>>>(agg, Wt + 0 * 65536, Wt + 1 * 65536,
                                             ss + 0 * 512, ss + 0 * 512 + 256, b2a, h1, N_NODES);

    // ---- layer 2 ----
    gather_ps<<<ggrid, 256, 0, stream>>>(h1, col, rowptr, agg);
    fused_mlp<<<MPAD / 64, 256, 0, stream>>>(agg, Wt + 2 * 65536, Wt + 3 * 65536,
                                             ss + 1 * 512, ss + 1 * 512 + 256, b2b, h2, N_NODES);

    // ---- pooling + head ----
    pool_seg<<<N_GRAPHS, 256, 0, stream>>>(h1, h2, gstart, pcat);
    dim3 h1grid(12, 8, KSPLIT);
    head1<<<h1grid, 256, 0, stream>>>(pcat, lin1_W, Hpart);
    head2<<<N_GRAPHS, 64, 0, stream>>>(Hpart, lin1_b, lin2_W, lin2_b, (float*)d_out);
}

// Round 15
// 364.676 us; speedup vs baseline: 1.5586x; 1.5586x over previous
//
#include <hip/hip_runtime.h>

#define N_NODES 50000
#define MPAD 50176            // 784*64, node-buffer row padding for GEMM staging
#define N_EDGES 800000
#define DIM 256
#define N_GRAPHS 500
#define N_OUT 10
#define BN_EPS 1e-5f
#define SCAN_BS 1024
#define KSPLIT 4
#define SORT_CAP 96           // max degree handled by sort (Poisson(16): P(deg>96) ~ 0)

typedef unsigned int u32;
typedef short bf16x8 __attribute__((ext_vector_type(8)));
typedef unsigned short us8 __attribute__((ext_vector_type(8)));
typedef float f32x4 __attribute__((ext_vector_type(4)));

typedef __attribute__((address_space(1))) const unsigned int gas_u32;
typedef __attribute__((address_space(3))) unsigned int las_u32;

__device__ inline void g2l16(const void* g, void* l) {
    // async global->LDS, 16 bytes per lane; LDS dest = wave-uniform base + lane*16
    __builtin_amdgcn_global_load_lds((gas_u32*)g, (las_u32*)l, 16, 0, 0);
}

__device__ inline float b2f(unsigned short u) {
    union { u32 i; float f; } c; c.i = ((u32)u) << 16; return c.f;
}
__device__ inline unsigned short f2b(float f) {   // round-to-nearest-even
    u32 x = __builtin_bit_cast(u32, f);
    return (unsigned short)((x + 0x7FFFu + ((x >> 16) & 1u)) >> 16);
}

// swizzled byte address into the 64x256-bf16 mid LDS tile (row stride 512B = 32 slots):
// slot ^= row&31 is bijective per row and de-conflicts stride-512B column reads.
__device__ inline int mid_addr(int row, int col) {
    return row * 512 + ((((col >> 3) ^ (row & 31)) << 4) | ((col & 7) << 1));
}

// ---------------- CSR build ----------------
__global__ void zero_i(int* __restrict__ p, int n) {
    int i = blockIdx.x * blockDim.x + threadIdx.x;
    if (i < n) p[i] = 0;
}
__global__ void hist_dst(const int* __restrict__ dst, int* __restrict__ deg) {
    int e = blockIdx.x * blockDim.x + threadIdx.x;
    if (e < N_EDGES) atomicAdd(&deg[dst[e]], 1);
}
__global__ void scan_phase1(const int* __restrict__ deg, int* __restrict__ rowptr,
                            int* __restrict__ bsum, int n) {
    __shared__ int sh[SCAN_BS];
    int i = blockIdx.x * SCAN_BS + threadIdx.x;
    int v = (i < n) ? deg[i] : 0;
    sh[threadIdx.x] = v;
    __syncthreads();
    for (int off = 1; off < SCAN_BS; off <<= 1) {
        int t = (threadIdx.x >= off) ? sh[threadIdx.x - off] : 0;
        __syncthreads();
        sh[threadIdx.x] += t;
        __syncthreads();
    }
    if (i < n) rowptr[i] = sh[threadIdx.x] - v;
    if (threadIdx.x == SCAN_BS - 1) bsum[blockIdx.x] = sh[threadIdx.x];
}
__global__ void scan_phase2(int* __restrict__ bsum, int nb) {
    if (threadIdx.x == 0 && blockIdx.x == 0) {
        int run = 0;
        for (int b = 0; b < nb; b++) { int v = bsum[b]; bsum[b] = run; run += v; }
    }
}
__global__ void scan_phase3(int* __restrict__ rowptr, int* __restrict__ cursor,
                            const int* __restrict__ bsum, int n) {
    int i = blockIdx.x * SCAN_BS + threadIdx.x;
    if (i < n) {
        int v = rowptr[i] + bsum[blockIdx.x];
        rowptr[i] = v;
        cursor[i] = v;
    }
    if (i == 0) rowptr[n] = N_EDGES;
}
__global__ void fill_csr(const int* __restrict__ src, const int* __restrict__ dst,
                         int* __restrict__ cursor, int* __restrict__ col) {
    int e = blockIdx.x * blockDim.x + threadIdx.x;
    if (e < N_EDGES) {
        int p = atomicAdd(&cursor[dst[e]], 1);
        col[p] = src[e];
    }
}
// canonicalize neighbor order (atomic fill order is nondeterministic -> f32 sum order
// would vary call-to-call; harness requires identical output every call).
__global__ void sort_csr(const int* __restrict__ rowptr, int* __restrict__ col) {
    __shared__ int buf[4][SORT_CAP];
    int node = blockIdx.x * 4 + (threadIdx.x >> 6);
    if (node >= N_NODES) return;
    int lane = threadIdx.x & 63;
    int w = threadIdx.x >> 6;
    int s = rowptr[node], e = rowptr[node + 1];
    int L = e - s;
    if (L <= 1 || L > SORT_CAP) return;
    for (int i = lane; i < L; i += 64) buf[w][i] = col[s + i];
    asm volatile("s_waitcnt lgkmcnt(0) vmcnt(0)" ::: "memory");
    for (int pass = 0; pass < L; pass++) {
        int base = 2 * lane + (pass & 1);
        if (base + 1 < L) {
            int a = buf[w][base], b = buf[w][base + 1];
            if (a > b) { buf[w][base] = b; buf[w][base + 1] = a; }
        }
        asm volatile("s_waitcnt lgkmcnt(0)" ::: "memory");
    }
    for (int i = lane; i < L; i += 64) col[s + i] = buf[w][i];
}
__global__ void graph_starts(const int* __restrict__ batch, int* __restrict__ gstart) {
    int g = blockIdx.x * blockDim.x + threadIdx.x;
    if (g > N_GRAPHS) return;
    if (g == N_GRAPHS) { gstart[g] = N_NODES; return; }
    int lo = 0, hi = N_NODES;
    while (lo < hi) { int mid = (lo + hi) >> 1; if (batch[mid] < g) lo = mid + 1; else hi = mid; }
    gstart[g] = lo;
}

// ---------------- conversions ----------------
__global__ void conv_x(const float4* __restrict__ in, ushort4* __restrict__ out, int n4) {
    int i = blockIdx.x * blockDim.x + threadIdx.x;
    if (i < n4) {
        float4 v = in[i];
        ushort4 o; o.x = f2b(v.x); o.y = f2b(v.y); o.z = f2b(v.z); o.w = f2b(v.w);
        out[i] = o;
    }
}
// Wt[mat][n][k] = bf16(W[mat][k][n])
__global__ void conv_wt4(const float* __restrict__ W0, const float* __restrict__ W1,
                         const float* __restrict__ W2, const float* __restrict__ W3,
                         unsigned short* __restrict__ Wt) {
    int mat = blockIdx.y;
    const float* W = (mat == 0) ? W0 : (mat == 1) ? W1 : (mat == 2) ? W2 : W3;
    int n = blockIdx.x;
    int k = threadIdx.x;
    Wt[((size_t)mat << 16) + (size_t)n * 256 + k] = f2b(W[(size_t)k * 256 + n]);
}
__global__ void make_ss(const float* __restrict__ bias, const float* __restrict__ gamma,
                        const float* __restrict__ beta, const float* __restrict__ mean,
                        const float* __restrict__ var, float* __restrict__ scale,
                        float* __restrict__ shift) {
    int i = threadIdx.x;
    float s = gamma[i] * rsqrtf(var[i] + BN_EPS);
    scale[i] = s;
    shift[i] = (bias[i] - mean[i]) * s + beta[i];
}

// ---------------- gather aggregate (bf16): out[i] = feat[i] + sum_{j in N(i)} feat[j] ----------------
// one wave per node; two 32-lane halves own alternate edges; 16 B/lane loads; x4 unroll (8 streams/wave).
__global__ void gather_bf(const unsigned short* __restrict__ feat,
                          const int* __restrict__ col,
                          const int* __restrict__ rowptr,
                          unsigned short* __restrict__ out) {
    int node = blockIdx.x * 4 + (threadIdx.x >> 6);
    if (node >= N_NODES) return;
    int lane = threadIdx.x & 63;
    int half = lane >> 5;
    int d8 = (lane & 31) * 8;          // 8 bf16 = 16 B per lane
    float acc[8];
    #pragma unroll
    for (int j = 0; j < 8; j++) acc[j] = 0.f;
    if (half == 0) {
        us8 own = *reinterpret_cast<const us8*>(&feat[(size_t)node * DIM + d8]);
        #pragma unroll
        for (int j = 0; j < 8; j++) acc[j] = b2f((unsigned short)own[j]);
    }
    int s = rowptr[node], e = rowptr[node + 1];
    int i = s + half;
    for (; i + 6 < e; i += 8) {        // 4 edges per half per iter
        int n0 = col[i], n1 = col[i + 2], n2 = col[i + 4], n3 = col[i + 6];
        us8 v0 = *reinterpret_cast<const us8*>(&feat[(size_t)n0 * DIM + d8]);
        us8 v1 = *reinterpret_cast<const us8*>(&feat[(size_t)n1 * DIM + d8]);
        us8 v2 = *reinterpret_cast<const us8*>(&feat[(size_t)n2 * DIM + d8]);
        us8 v3 = *reinterpret_cast<const us8*>(&feat[(size_t)n3 * DIM + d8]);
        #pragma unroll
        for (int j = 0; j < 8; j++)
            acc[j] += (b2f((unsigned short)v0[j]) + b2f((unsigned short)v1[j]))
                    + (b2f((unsigned short)v2[j]) + b2f((unsigned short)v3[j]));
    }
    for (; i < e; i += 2) {
        int n0 = col[i];
        us8 v0 = *reinterpret_cast<const us8*>(&feat[(size_t)n0 * DIM + d8]);
        #pragma unroll
        for (int j = 0; j < 8; j++) acc[j] += b2f((unsigned short)v0[j]);
    }
    #pragma unroll
    for (int j = 0; j < 8; j++) acc[j] += __shfl_xor(acc[j], 32, 64);
    if (half == 0) {
        us8 o;
        #pragma unroll
        for (int j = 0; j < 8; j++) o[j] = (short)f2b(acc[j]);
        *reinterpret_cast<us8*>(&out[(size_t)node * DIM + d8]) = o;
    }
}

// ---------------- fused GIN MLP:  H = relu(relu(bn(A@W1)) @ W2 + b2), all in one block pass ------
// 256 threads, 64-row tile, 4 waves as 1M x 4N (wave 64x64), BK=32, K=256.
// Conservative sync: __syncthreads() full drains only (R13-proven).
__global__ __launch_bounds__(256, 2)
void fused_mlp(const unsigned short* __restrict__ A,
               const unsigned short* __restrict__ W1t,   // [256][256], W1t[n][k]
               const unsigned short* __restrict__ W2t,   // [256][256], W2t[n][k]
               const float* __restrict__ scale1,
               const float* __restrict__ shift1,
               const float* __restrict__ shift2,         // b2
               unsigned short* __restrict__ H, int M) {
    __shared__ __align__(16) unsigned short Asb[2][64 * 32];    // 2 x 4 KB
    __shared__ __align__(16) unsigned short Bsb[2][256 * 32];   // 2 x 16 KB
    __shared__ __align__(16) unsigned short midb[64 * 256];     // 32 KB, swizzled

    int t = threadIdx.x;
    int wave = t >> 6, lane = t & 63;
    int m0 = blockIdx.x * 64;
    int wc = wave * 64;
    int rsel = lane & 15;
    int ksel = (lane >> 4) * 8;
    int cr = lane >> 4;

    float s1[4], sh1[4], sh2[4];
    #pragma unroll
    for (int n = 0; n < 4; n++) {
        int colg = wc + n * 16 + rsel;
        s1[n]  = scale1[colg];
        sh1[n] = shift1[colg];
        sh2[n] = shift2[colg];
    }

    int cb = (t & 3) * 16;
    const char* Ab  = (const char*)A   + (size_t)(m0 + (t >> 2)) * 512 + cb;
    const char* B1b = (const char*)W1t + (size_t)(t >> 2) * 512 + cb;
    const char* B2b = (const char*)W2t + (size_t)(t >> 2) * 512 + cb;

    f32x4 acc[4][4];
    #pragma unroll
    for (int m = 0; m < 4; m++)
        #pragma unroll
        for (int n = 0; n < 4; n++)
            acc[m][n] = (f32x4){0.f, 0.f, 0.f, 0.f};

    // prologue: stage phase-1 tiles 0,1
    #pragma unroll
    for (int p = 0; p < 2; p++) {
        size_t ko = (size_t)p * 64;
        g2l16(Ab + ko, (char*)Asb[p] + (size_t)t * 16);
        #pragma unroll
        for (int i = 0; i < 4; i++)
            g2l16(B1b + (size_t)i * 32768 + ko, (char*)Bsb[p] + (size_t)(i * 256 + t) * 16);
    }

    // ---- phase 1: acc = A @ W1 ----
    #pragma unroll
    for (int ks = 0; ks < 8; ks++) {
        const int cur = ks & 1;
        __syncthreads();   // tile ks staged (full vm+lgkm drain)

        const unsigned short* As = Asb[cur];
        const unsigned short* Bs = Bsb[cur];
        bf16x8 af[4], bfr[4];
        #pragma unroll
        for (int m = 0; m < 4; m++)
            af[m] = *(const bf16x8*)&As[(size_t)(m * 16 + rsel) * 32 + ksel];
        #pragma unroll
        for (int n = 0; n < 4; n++)
            bfr[n] = *(const bf16x8*)&Bs[(size_t)(wc + n * 16 + rsel) * 32 + ksel];
        #pragma unroll
        for (int m = 0; m < 4; m++)
            #pragma unroll
            for (int n = 0; n < 4; n++)
                acc[m][n] = __builtin_amdgcn_mfma_f32_16x16x32_bf16(af[m], bfr[n], acc[m][n], 0, 0, 0);

        __syncthreads();   // all waves done reading buf[cur]
        if (ks + 2 < 8) {            // restage buf[cur] with phase-1 tile ks+2
            size_t ko = (size_t)(ks + 2) * 64;
            g2l16(Ab + ko, (char*)Asb[cur] + (size_t)t * 16);
            #pragma unroll
            for (int i = 0; i < 4; i++)
                g2l16(B1b + (size_t)i * 32768 + ko, (char*)Bsb[cur] + (size_t)(i * 256 + t) * 16);
        } else if (ks == 6) {        // Bsb[0] free -> prefetch W2 tile 0
            #pragma unroll
            for (int i = 0; i < 4; i++)
                g2l16(B2b + (size_t)i * 32768, (char*)Bsb[0] + (size_t)(i * 256 + t) * 16);
        } else {                     // ks == 7: Bsb[1] free -> prefetch W2 tile 1
            #pragma unroll
            for (int i = 0; i < 4; i++)
                g2l16(B2b + (size_t)i * 32768 + 64, (char*)Bsb[1] + (size_t)(i * 256 + t) * 16);
        }
    }

    // ---- epilogue 1: mid = relu(acc*scale1 + shift1) -> bf16 -> swizzled LDS; reset acc ----
    #pragma unroll
    for (int n = 0; n < 4; n++) {
        int colg = wc + n * 16 + rsel;
        #pragma unroll
        for (int m = 0; m < 4; m++) {
            int rowb = m * 16 + cr * 4;
            #pragma unroll
            for (int r = 0; r < 4; r++) {
                float v = fmaxf(acc[m][n][r] * s1[n] + sh1[n], 0.f);
                *(unsigned short*)((char*)midb + mid_addr(rowb + r, colg)) = f2b(v);
                acc[m][n][r] = 0.f;
            }
        }
    }

    // ---- phase 2: acc = mid @ W2 ----
    #pragma unroll
    for (int ks = 0; ks < 8; ks++) {
        const int cur = ks & 1;
        __syncthreads();   // W2 tile ks staged; (first iter) midb writes visible

        const unsigned short* Bs = Bsb[cur];
        bf16x8 af[4], bfr[4];
        #pragma unroll
        for (int m = 0; m < 4; m++)
            af[m] = *(const bf16x8*)((const char*)midb + mid_addr(m * 16 + rsel, ks * 32 + ksel));
        #pragma unroll
        for (int n = 0; n < 4; n++)
            bfr[n] = *(const bf16x8*)&Bs[(size_t)(wc + n * 16 + rsel) * 32 + ksel];
        #pragma unroll
        for (int m = 0; m < 4; m++)
            #pragma unroll
            for (int n = 0; n < 4; n++)
                acc[m][n] = __builtin_amdgcn_mfma_f32_16x16x32_bf16(af[m], bfr[n], acc[m][n], 0, 0, 0);

        __syncthreads();   // all waves done reading buf[cur]
        if (ks + 2 < 8) {            // restage buf[cur] with W2 tile ks+2
            size_t ko = (size_t)(ks + 2) * 64;
            #pragma unroll
            for (int i = 0; i < 4; i++)
                g2l16(B2b + (size_t)i * 32768 + ko, (char*)Bsb[cur] + (size_t)(i * 256 + t) * 16);
        }
    }

    // ---- epilogue 2: H = relu(acc + b2) ----
    #pragma unroll
    for (int n = 0; n < 4; n++) {
        int colg = wc + n * 16 + rsel;
        #pragma unroll
        for (int m = 0; m < 4; m++) {
            int rowb = m0 + m * 16 + cr * 4;
            #pragma unroll
            for (int r = 0; r < 4; r++) {
                int row = rowb + r;
                if (row < M) {
                    float v = fmaxf(acc[m][n][r] + sh2[n], 0.f);
                    H[(size_t)row * 256 + colg] = f2b(v);
                }
            }
        }
    }
}

// ---------------- pooling v2: vectorized us8 loads, LDS fixed-order reduction ----------------
// 256 threads = 8 node-groups x 32 lanes; each lane loads 16 B (8 bf16) per row.
// Deterministic: per-thread node order fixed, cross-group sum in fixed k order.
__global__ void pool_seg(const unsigned short* __restrict__ h1,
                         const unsigned short* __restrict__ h2,
                         const int* __restrict__ gstart,
                         float* __restrict__ pcat) {
    __shared__ float red1[8][256];
    __shared__ float red2[8][256];
    int g = blockIdx.x;
    int t = threadIdx.x;
    int sub = t >> 5;              // node-group 0..7
    int d8 = (t & 31) * 8;         // element offset within row
    float a1[8], a2[8];
    #pragma unroll
    for (int j = 0; j < 8; j++) { a1[j] = 0.f; a2[j] = 0.f; }
    int s = gstart[g], e = gstart[g + 1];
    for (int n = s + sub; n < e; n += 8) {
        us8 v1 = *reinterpret_cast<const us8*>(&h1[(size_t)n * DIM + d8]);
        us8 v2 = *reinterpret_cast<const us8*>(&h2[(size_t)n * DIM + d8]);
        #pragma unroll
        for (int j = 0; j < 8; j++) {
            a1[j] += b2f((unsigned short)v1[j]);
            a2[j] += b2f((unsigned short)v2[j]);
        }
    }
    #pragma unroll
    for (int j = 0; j < 8; j++) {
        red1[sub][d8 + j] = a1[j];
        red2[sub][d8 + j] = a2[j];
    }
    __syncthreads();
    // thread t reduces element t (layer1) and element t (layer2), fixed k order
    float o1 = 0.f, o2 = 0.f;
    #pragma unroll
    for (int k = 0; k < 8; k++) { o1 += red1[k][t]; o2 += red2[k][t]; }
    pcat[(size_t)g * 512 + t]       = o1;
    pcat[(size_t)g * 512 + 256 + t] = o2;
}

// ---------------- head stage 1 (split-K): Hpart[z][500][768] = pcat[:, z*128:(z+1)*128] @ W1-slice ----
__global__ void head1(const float* __restrict__ A,    // [500][512]
                      const float* __restrict__ W1,   // [512][768]
                      float* __restrict__ Hpart) {    // [KSPLIT][500][768]
    __shared__ float As[16][65];
    __shared__ float Bs[16][65];
    int t = threadIdx.x;
    int m0 = blockIdx.y * 64;
    int n0 = blockIdx.x * 64;
    int kz = blockIdx.z * (512 / KSPLIT);
    int tx = t & 15, ty = t >> 4;
    float acc[4][4] = {};
    for (int k0 = kz; k0 < kz + 512 / KSPLIT; k0 += 16) {
        #pragma unroll
        for (int i = 0; i < 4; i++) {
            int r = (t >> 4) + i * 16;
            int k = t & 15;
            int gr = m0 + r;
            As[k][r] = (gr < N_GRAPHS) ? A[(size_t)gr * 512 + k0 + k] : 0.f;
        }
        #pragma unroll
        for (int i = 0; i < 4; i++) {
            int k = (t >> 6) + i * 4;
            int n = t & 63;
            Bs[k][n] = W1[(size_t)(k0 + k) * 768 + n0 + n];
        }
        __syncthreads();
        #pragma unroll
        for (int k = 0; k < 16; k++) {
            float a[4], b[4];
            #pragma unroll
            for (int i = 0; i < 4; i++) a[i] = As[k][ty * 4 + i];
            #pragma unroll
            for (int j = 0; j < 4; j++) b[j] = Bs[k][tx * 4 + j];
            #pragma unroll
            for (int i = 0; i < 4; i++)
                #pragma unroll
                for (int j = 0; j < 4; j++)
                    acc[i][j] += a[i] * b[j];
        }
        __syncthreads();
    }
    float* Hz = Hpart + (size_t)blockIdx.z * N_GRAPHS * 768;
    #pragma unroll
    for (int i = 0; i < 4; i++) {
        int gm = m0 + ty * 4 + i;
        if (gm >= N_GRAPHS) continue;
        #pragma unroll
        for (int j = 0; j < 4; j++) {
            int gn = n0 + tx * 4 + j;
            Hz[(size_t)gm * 768 + gn] = acc[i][j];
        }
    }
}

// ---------------- head stage 2: sum partials + bias + relu, GEMV, log_softmax ----------------
__global__ void head2(const float* __restrict__ Hpart, const float* __restrict__ b1,
                      const float* __restrict__ W2, const float* __restrict__ b2,
                      float* __restrict__ out) {
    int g = blockIdx.x;
    int lane = threadIdx.x;   // 64
    float part[N_OUT];
    #pragma unroll
    for (int o = 0; o < N_OUT; o++) part[o] = 0.f;
    for (int k = lane; k < 768; k += 64) {
        float hv = b1[k];
        #pragma unroll
        for (int z = 0; z < KSPLIT; z++)
            hv += Hpart[((size_t)z * N_GRAPHS + g) * 768 + k];
        hv = fmaxf(hv, 0.f);
        #pragma unroll
        for (int o = 0; o < N_OUT; o++) part[o] += hv * W2[(size_t)k * N_OUT + o];
    }
    #pragma unroll
    for (int o = 0; o < N_OUT; o++) {
        #pragma unroll
        for (int off = 32; off > 0; off >>= 1)
            part[o] += __shfl_down(part[o], off, 64);
    }
    if (lane == 0) {
        float logits[N_OUT];
        float mx = -1e30f;
        #pragma unroll
        for (int o = 0; o < N_OUT; o++) { logits[o] = part[o] + b2[o]; mx = fmaxf(mx, logits[o]); }
        float ssum = 0.f;
        #pragma unroll
        for (int o = 0; o < N_OUT; o++) ssum += expf(logits[o] - mx);
        float lse = logf(ssum);
        #pragma unroll
        for (int o = 0; o < N_OUT; o++)
            out[(size_t)g * N_OUT + o] = logits[o] - mx - lse;
    }
}

extern "C" void kernel_launch(void* const* d_in, const int* in_sizes, int n_in,
                              void* d_out, int out_size, void* d_ws, size_t ws_size,
                              hipStream_t stream) {
    const float* x     = (const float*)d_in[0];
    const int*   ei    = (const int*)d_in[1];
    const int*   batch = (const int*)d_in[2];
    const float* W1a = (const float*)d_in[3];
    const float* b1a = (const float*)d_in[4];
    const float* g1a = (const float*)d_in[5];
    const float* be1a= (const float*)d_in[6];
    const float* m1a = (const float*)d_in[7];
    const float* v1a = (const float*)d_in[8];
    const float* W2a = (const float*)d_in[9];
    const float* b2a = (const float*)d_in[10];
    const float* W1b = (const float*)d_in[11];
    const float* b1b = (const float*)d_in[12];
    const float* g1b = (const float*)d_in[13];
    const float* be1b= (const float*)d_in[14];
    const float* m1b = (const float*)d_in[15];
    const float* v1b = (const float*)d_in[16];
    const float* W2b = (const float*)d_in[17];
    const float* b2b = (const float*)d_in[18];
    const float* lin1_W = (const float*)d_in[19];
    const float* lin1_b = (const float*)d_in[20];
    const float* lin2_W = (const float*)d_in[21];
    const float* lin2_b = (const float*)d_in[22];

    const size_t NBUF = (size_t)MPAD * DIM;
    char* ws = (char*)d_ws;
    unsigned short* agg  = (unsigned short*)ws;            ws += NBUF * 2;
    unsigned short* h1   = (unsigned short*)ws;            ws += NBUF * 2;
    unsigned short* h2   = (unsigned short*)ws;            ws += NBUF * 2;
    unsigned short* x_bf = (unsigned short*)ws;            ws += (size_t)N_NODES * DIM * 2;
    unsigned short* Wt   = (unsigned short*)ws;            ws += 4 * 65536 * 2;
    float* ss    = (float*)ws;                             ws += 4 * 256 * 4;   // 2x(scale,shift)
    float* pcat  = (float*)ws;                             ws += (size_t)N_GRAPHS * 512 * 4;
    float* Hpart = (float*)ws;                             ws += (size_t)KSPLIT * N_GRAPHS * 768 * 4;
    int* deg     = (int*)ws;                               ws += (size_t)N_NODES * 4;
    int* cursor  = (int*)ws;                               ws += (size_t)N_NODES * 4;
    int* rowptr  = (int*)ws;                               ws += (size_t)(N_NODES + 1) * 4;
    int* bsum    = (int*)ws;                               ws += 64 * 4;
    int* col     = (int*)ws;                               ws += (size_t)N_EDGES * 4;
    int* gstart  = (int*)ws;

    const int* srcE = ei;
    const int* dstE = ei + N_EDGES;

    const int nscan = (N_NODES + SCAN_BS - 1) / SCAN_BS;

    // ---- CSR build (by dst), shared by both layers; sorted for determinism ----
    zero_i<<<(N_NODES + 255) / 256, 256, 0, stream>>>(deg, N_NODES);
    hist_dst<<<(N_EDGES + 255) / 256, 256, 0, stream>>>(dstE, deg);
    scan_phase1<<<nscan, SCAN_BS, 0, stream>>>(deg, rowptr, bsum, N_NODES);
    scan_phase2<<<1, 64, 0, stream>>>(bsum, nscan);
    scan_phase3<<<nscan, SCAN_BS, 0, stream>>>(rowptr, cursor, bsum, N_NODES);
    fill_csr<<<(N_EDGES + 255) / 256, 256, 0, stream>>>(srcE, dstE, cursor, col);
    sort_csr<<<(N_NODES + 3) / 4, 256, 0, stream>>>(rowptr, col);
    graph_starts<<<2, 256, 0, stream>>>(batch, gstart);

    // ---- precompute ----
    conv_x<<<(N_NODES * DIM / 4 + 255) / 256, 256, 0, stream>>>(
        (const float4*)x, (ushort4*)x_bf, N_NODES * DIM / 4);
    dim3 wt_grid(256, 4);
    conv_wt4<<<wt_grid, 256, 0, stream>>>(W1a, W2a, W1b, W2b, Wt);
    make_ss<<<1, 256, 0, stream>>>(b1a, g1a, be1a, m1a, v1a, ss + 0 * 512, ss + 0 * 512 + 256);
    make_ss<<<1, 256, 0, stream>>>(b1b, g1b, be1b, m1b, v1b, ss + 1 * 512, ss + 1 * 512 + 256);

    // ---- layer 1 ----
    gather_bf<<<(N_NODES + 3) / 4, 256, 0, stream>>>(x_bf, col, rowptr, agg);
    fused_mlp<<<MPAD / 64, 256, 0, stream>>>(agg, Wt + 0 * 65536, Wt + 1 * 65536,
                                             ss + 0 * 512, ss + 0 * 512 + 256, b2a, h1, N_NODES);

    // ---- layer 2 ----
    gather_bf<<<(N_NODES + 3) / 4, 256, 0, stream>>>(h1, col, rowptr, agg);
    fused_mlp<<<MPAD / 64, 256, 0, stream>>>(agg, Wt + 2 * 65536, Wt + 3 * 65536,
                                             ss + 1 * 512, ss + 1 * 512 + 256, b2b, h2, N_NODES);

    // ---- pooling + head ----
    pool_seg<<<N_GRAPHS, 256, 0, stream>>>(h1, h2, gstart, pcat);
    dim3 h1grid(12, 8, KSPLIT);
    head1<<<h1grid, 256, 0, stream>>>(pcat, lin1_W, Hpart);
    head2<<<N_GRAPHS, 64, 0, stream>>>(Hpart, lin1_b, lin2_W, lin2_b, (float*)d_out);
}

// Round 16
// 361.426 us; speedup vs baseline: 1.5726x; 1.0090x over previous
//
#include <hip/hip_runtime.h>

#define N_NODES 50000
#define MPAD 50176            // 784*64, node-buffer row padding for GEMM staging
#define N_EDGES 800000
#define DIM 256
#define N_GRAPHS 500
#define N_OUT 10
#define BN_EPS 1e-5f
#define SCAN_BS 1024
#define KSPLIT 4
#define SORT_CAP 96           // max degree handled by sort (Poisson(16): P(deg>96) ~ 0)

typedef unsigned int u32;
typedef short bf16x8 __attribute__((ext_vector_type(8)));
typedef unsigned short us8 __attribute__((ext_vector_type(8)));
typedef float f32x4 __attribute__((ext_vector_type(4)));

typedef __attribute__((address_space(1))) const unsigned int gas_u32;
typedef __attribute__((address_space(3))) unsigned int las_u32;

__device__ inline void g2l16(const void* g, void* l) {
    // async global->LDS, 16 bytes per lane; LDS dest = wave-uniform base + lane*16
    __builtin_amdgcn_global_load_lds((gas_u32*)g, (las_u32*)l, 16, 0, 0);
}

__device__ inline float b2f(unsigned short u) {
    union { u32 i; float f; } c; c.i = ((u32)u) << 16; return c.f;
}
__device__ inline unsigned short f2b(float f) {   // round-to-nearest-even
    u32 x = __builtin_bit_cast(u32, f);
    return (unsigned short)((x + 0x7FFFu + ((x >> 16) & 1u)) >> 16);
}

// swizzled byte address into the 64x256-bf16 mid LDS tile (row stride 512B = 32 slots):
// slot ^= row&31 is bijective per row and de-conflicts stride-512B column reads.
__device__ inline int mid_addr(int row, int col) {
    return row * 512 + ((((col >> 3) ^ (row & 31)) << 4) | ((col & 7) << 1));
}

// ---------------- CSR build ----------------
__global__ void zero_i(int* __restrict__ p, int n) {
    int i = blockIdx.x * blockDim.x + threadIdx.x;
    if (i < n) p[i] = 0;
}
__global__ void hist_dst(const int* __restrict__ dst, int* __restrict__ deg) {
    int e = blockIdx.x * blockDim.x + threadIdx.x;
    if (e < N_EDGES) atomicAdd(&deg[dst[e]], 1);
}
__global__ void scan_phase1(const int* __restrict__ deg, int* __restrict__ rowptr,
                            int* __restrict__ bsum, int n) {
    __shared__ int sh[SCAN_BS];
    int i = blockIdx.x * SCAN_BS + threadIdx.x;
    int v = (i < n) ? deg[i] : 0;
    sh[threadIdx.x] = v;
    __syncthreads();
    for (int off = 1; off < SCAN_BS; off <<= 1) {
        int t = (threadIdx.x >= off) ? sh[threadIdx.x - off] : 0;
        __syncthreads();
        sh[threadIdx.x] += t;
        __syncthreads();
    }
    if (i < n) rowptr[i] = sh[threadIdx.x] - v;
    if (threadIdx.x == SCAN_BS - 1) bsum[blockIdx.x] = sh[threadIdx.x];
}
__global__ void scan_phase2(int* __restrict__ bsum, int nb) {
    if (threadIdx.x == 0 && blockIdx.x == 0) {
        int run = 0;
        for (int b = 0; b < nb; b++) { int v = bsum[b]; bsum[b] = run; run += v; }
    }
}
__global__ void scan_phase3(int* __restrict__ rowptr, int* __restrict__ cursor,
                            const int* __restrict__ bsum, int n) {
    int i = blockIdx.x * SCAN_BS + threadIdx.x;
    if (i < n) {
        int v = rowptr[i] + bsum[blockIdx.x];
        rowptr[i] = v;
        cursor[i] = v;
    }
    if (i == 0) rowptr[n] = N_EDGES;
}
__global__ void fill_csr(const int* __restrict__ src, const int* __restrict__ dst,
                         int* __restrict__ cursor, int* __restrict__ col) {
    int e = blockIdx.x * blockDim.x + threadIdx.x;
    if (e < N_EDGES) {
        int p = atomicAdd(&cursor[dst[e]], 1);
        col[p] = src[e];
    }
}
// canonicalize neighbor order (atomic fill order is nondeterministic -> f32 sum order
// would vary call-to-call; harness requires identical output every call).
__global__ void sort_csr(const int* __restrict__ rowptr, int* __restrict__ col) {
    __shared__ int buf[4][SORT_CAP];
    int node = blockIdx.x * 4 + (threadIdx.x >> 6);
    if (node >= N_NODES) return;
    int lane = threadIdx.x & 63;
    int w = threadIdx.x >> 6;
    int s = rowptr[node], e = rowptr[node + 1];
    int L = e - s;
    if (L <= 1 || L > SORT_CAP) return;
    for (int i = lane; i < L; i += 64) buf[w][i] = col[s + i];
    asm volatile("s_waitcnt lgkmcnt(0) vmcnt(0)" ::: "memory");
    for (int pass = 0; pass < L; pass++) {
        int base = 2 * lane + (pass & 1);
        if (base + 1 < L) {
            int a = buf[w][base], b = buf[w][base + 1];
            if (a > b) { buf[w][base] = b; buf[w][base + 1] = a; }
        }
        asm volatile("s_waitcnt lgkmcnt(0)" ::: "memory");
    }
    for (int i = lane; i < L; i += 64) col[s + i] = buf[w][i];
}
__global__ void graph_starts(const int* __restrict__ batch, int* __restrict__ gstart) {
    int g = blockIdx.x * blockDim.x + threadIdx.x;
    if (g > N_GRAPHS) return;
    if (g == N_GRAPHS) { gstart[g] = N_NODES; return; }
    int lo = 0, hi = N_NODES;
    while (lo < hi) { int mid = (lo + hi) >> 1; if (batch[mid] < g) lo = mid + 1; else hi = mid; }
    gstart[g] = lo;
}

// ---------------- conversions ----------------
__global__ void conv_x(const float4* __restrict__ in, ushort4* __restrict__ out, int n4) {
    int i = blockIdx.x * blockDim.x + threadIdx.x;
    if (i < n4) {
        float4 v = in[i];
        ushort4 o; o.x = f2b(v.x); o.y = f2b(v.y); o.z = f2b(v.z); o.w = f2b(v.w);
        out[i] = o;
    }
}
// Wt[mat][n][k] = bf16(W[mat][k][n])
__global__ void conv_wt4(const float* __restrict__ W0, const float* __restrict__ W1,
                         const float* __restrict__ W2, const float* __restrict__ W3,
                         unsigned short* __restrict__ Wt) {
    int mat = blockIdx.y;
    const float* W = (mat == 0) ? W0 : (mat == 1) ? W1 : (mat == 2) ? W2 : W3;
    int n = blockIdx.x;
    int k = threadIdx.x;
    Wt[((size_t)mat << 16) + (size_t)n * 256 + k] = f2b(W[(size_t)k * 256 + n]);
}
__global__ void make_ss(const float* __restrict__ bias, const float* __restrict__ gamma,
                        const float* __restrict__ beta, const float* __restrict__ mean,
                        const float* __restrict__ var, float* __restrict__ scale,
                        float* __restrict__ shift) {
    int i = threadIdx.x;
    float s = gamma[i] * rsqrtf(var[i] + BN_EPS);
    scale[i] = s;
    shift[i] = (bias[i] - mean[i]) * s + beta[i];
}

// ---------------- gather aggregate (bf16): out[i] = feat[i] + sum_{j in N(i)} feat[j] ----------------
// one wave per node; two 32-lane halves own alternate edges; 16 B/lane loads; x4 unroll (8 streams/wave).
__global__ void gather_bf(const unsigned short* __restrict__ feat,
                          const int* __restrict__ col,
                          const int* __restrict__ rowptr,
                          unsigned short* __restrict__ out) {
    int node = blockIdx.x * 4 + (threadIdx.x >> 6);
    if (node >= N_NODES) return;
    int lane = threadIdx.x & 63;
    int half = lane >> 5;
    int d8 = (lane & 31) * 8;          // 8 bf16 = 16 B per lane
    float acc[8];
    #pragma unroll
    for (int j = 0; j < 8; j++) acc[j] = 0.f;
    if (half == 0) {
        us8 own = *reinterpret_cast<const us8*>(&feat[(size_t)node * DIM + d8]);
        #pragma unroll
        for (int j = 0; j < 8; j++) acc[j] = b2f((unsigned short)own[j]);
    }
    int s = rowptr[node], e = rowptr[node + 1];
    int i = s + half;
    for (; i + 6 < e; i += 8) {        // 4 edges per half per iter
        int n0 = col[i], n1 = col[i + 2], n2 = col[i + 4], n3 = col[i + 6];
        us8 v0 = *reinterpret_cast<const us8*>(&feat[(size_t)n0 * DIM + d8]);
        us8 v1 = *reinterpret_cast<const us8*>(&feat[(size_t)n1 * DIM + d8]);
        us8 v2 = *reinterpret_cast<const us8*>(&feat[(size_t)n2 * DIM + d8]);
        us8 v3 = *reinterpret_cast<const us8*>(&feat[(size_t)n3 * DIM + d8]);
        #pragma unroll
        for (int j = 0; j < 8; j++)
            acc[j] += (b2f((unsigned short)v0[j]) + b2f((unsigned short)v1[j]))
                    + (b2f((unsigned short)v2[j]) + b2f((unsigned short)v3[j]));
    }
    for (; i < e; i += 2) {
        int n0 = col[i];
        us8 v0 = *reinterpret_cast<const us8*>(&feat[(size_t)n0 * DIM + d8]);
        #pragma unroll
        for (int j = 0; j < 8; j++) acc[j] += b2f((unsigned short)v0[j]);
    }
    #pragma unroll
    for (int j = 0; j < 8; j++) acc[j] += __shfl_xor(acc[j], 32, 64);
    if (half == 0) {
        us8 o;
        #pragma unroll
        for (int j = 0; j < 8; j++) o[j] = (short)f2b(acc[j]);
        *reinterpret_cast<us8*>(&out[(size_t)node * DIM + d8]) = o;
    }
}

// ---------------- fused GIN MLP v3:  H = relu(relu(bn(A@W1)) @ W2 + b2) ------
// 256 threads, 64-row tile, 4 waves as 1M x 4N (wave 64x64), BK=64, K=256 -> 4 steps/phase.
// Single-buffered staging (full-drain __syncthreads only; with full drains, double-
// buffering gives zero overlap anyway -- fewer, bigger steps = fewer exposed drains).
// A/B LDS tiles XOR-swizzled (G4): 16B chunk c of row r stored at c^(r&7); swizzle is
// applied to the GLOBAL SOURCE address (LDS dest stays linear for global_load_lds),
// reads apply the same involution -> ~2-way bank aliasing instead of 8/16-way.
__global__ __launch_bounds__(256, 2)
void fused_mlp(const unsigned short* __restrict__ A,
               const unsigned short* __restrict__ W1t,   // [256][256], W1t[n][k]
               const unsigned short* __restrict__ W2t,   // [256][256], W2t[n][k]
               const float* __restrict__ scale1,
               const float* __restrict__ shift1,
               const float* __restrict__ shift2,         // b2
               unsigned short* __restrict__ H, int M) {
    __shared__ __align__(16) unsigned short Asb[64 * 64];    // 8 KB  (64 rows x 64 k)
    __shared__ __align__(16) unsigned short Bsb[256 * 64];   // 32 KB (256 n x 64 k)
    __shared__ __align__(16) unsigned short midb[64 * 256];  // 32 KB, mid_addr swizzle

    int t = threadIdx.x;
    int wave = t >> 6, lane = t & 63;
    int m0 = blockIdx.x * 64;
    int wc = wave * 64;
    int rsel = lane & 15;
    int kgrp = lane >> 4;            // 16B chunk-in-subtile 0..3
    int cr = lane >> 4;

    float s1[4], sh1[4], sh2[4];
    #pragma unroll
    for (int n = 0; n < 4; n++) {
        int colg = wc + n * 16 + rsel;
        s1[n]  = scale1[colg];
        sh1[n] = shift1[colg];
        sh2[n] = shift2[colg];
    }

    f32x4 acc[4][4];
    #pragma unroll
    for (int m = 0; m < 4; m++)
        #pragma unroll
        for (int n = 0; n < 4; n++)
            acc[m][n] = (f32x4){0.f, 0.f, 0.f, 0.f};

    // staging slot geometry: slot s -> row = s>>3, chunk = s&7 (8 x 16B chunks = 128B/row)
    // source chunk is XOR-swizzled so linear LDS holds chunk (c ^ (row&7)) at slot c.
    int arow0 = t >> 3, achk0 = t & 7;                  // A slots t, 256+t
    int arow1 = (256 + t) >> 3, achk1 = t & 7;          // (256+t)&7 == t&7
    const char* Abase = (const char*)A + (size_t)m0 * 512;

    // ---- phase 1: acc = A @ W1 ----
    for (int ks = 0; ks < 4; ks++) {
        size_t ko = (size_t)ks * 128;   // 64 bf16 = 128 B per K-step
        // A tile: 512 slots, 2 issues/thread
        g2l16(Abase + (size_t)arow0 * 512 + ko + ((achk0 ^ (arow0 & 7)) << 4),
              (char*)Asb + (size_t)t * 16);
        g2l16(Abase + (size_t)arow1 * 512 + ko + ((achk1 ^ (arow1 & 7)) << 4),
              (char*)Asb + (size_t)(256 + t) * 16);
        // B tile: 2048 slots, 8 issues/thread
        #pragma unroll
        for (int i = 0; i < 8; i++) {
            int s = i * 256 + t;
            int brow = s >> 3, bchk = s & 7;
            g2l16((const char*)W1t + (size_t)brow * 512 + ko + ((bchk ^ (brow & 7)) << 4),
                  (char*)Bsb + (size_t)s * 16);
        }
        __syncthreads();   // full drain: tile visible

        #pragma unroll
        for (int ksub = 0; ksub < 2; ksub++) {
            bf16x8 af[4], bfr[4];
            int kchunk = ksub * 4 + kgrp;   // global 16B chunk 0..7 within the 128B row
            #pragma unroll
            for (int m = 0; m < 4; m++) {
                int row = m * 16 + rsel;
                af[m] = *(const bf16x8*)((const char*)Asb + (size_t)row * 128
                                         + ((kchunk ^ (row & 7)) << 4));
            }
            #pragma unroll
            for (int n = 0; n < 4; n++) {
                int row = wc + n * 16 + rsel;
                bfr[n] = *(const bf16x8*)((const char*)Bsb + (size_t)row * 128
                                          + ((kchunk ^ (row & 7)) << 4));
            }
            #pragma unroll
            for (int m = 0; m < 4; m++)
                #pragma unroll
                for (int n = 0; n < 4; n++)
                    acc[m][n] = __builtin_amdgcn_mfma_f32_16x16x32_bf16(af[m], bfr[n], acc[m][n], 0, 0, 0);
        }
        __syncthreads();   // all waves done reading before restage
    }

    // ---- epilogue 1: mid = relu(acc*scale1 + shift1) -> bf16 -> swizzled LDS; reset acc ----
    #pragma unroll
    for (int n = 0; n < 4; n++) {
        int colg = wc + n * 16 + rsel;
        #pragma unroll
        for (int m = 0; m < 4; m++) {
            int rowb = m * 16 + cr * 4;
            #pragma unroll
            for (int r = 0; r < 4; r++) {
                float v = fmaxf(acc[m][n][r] * s1[n] + sh1[n], 0.f);
                *(unsigned short*)((char*)midb + mid_addr(rowb + r, colg)) = f2b(v);
                acc[m][n][r] = 0.f;
            }
        }
    }

    // ---- phase 2: acc = mid @ W2 ----
    for (int ks = 0; ks < 4; ks++) {
        size_t ko = (size_t)ks * 128;
        #pragma unroll
        for (int i = 0; i < 8; i++) {
            int s = i * 256 + t;
            int brow = s >> 3, bchk = s & 7;
            g2l16((const char*)W2t + (size_t)brow * 512 + ko + ((bchk ^ (brow & 7)) << 4),
                  (char*)Bsb + (size_t)s * 16);
        }
        __syncthreads();   // W2 tile staged; (first iter) midb writes visible

        #pragma unroll
        for (int ksub = 0; ksub < 2; ksub++) {
            bf16x8 af[4], bfr[4];
            int kchunk = ksub * 4 + kgrp;
            int kcol = ks * 64 + ksub * 32 + kgrp * 8;   // element col in mid
            #pragma unroll
            for (int m = 0; m < 4; m++)
                af[m] = *(const bf16x8*)((const char*)midb + mid_addr(m * 16 + rsel, kcol));
            #pragma unroll
            for (int n = 0; n < 4; n++) {
                int row = wc + n * 16 + rsel;
                bfr[n] = *(const bf16x8*)((const char*)Bsb + (size_t)row * 128
                                          + ((kchunk ^ (row & 7)) << 4));
            }
            #pragma unroll
            for (int m = 0; m < 4; m++)
                #pragma unroll
                for (int n = 0; n < 4; n++)
                    acc[m][n] = __builtin_amdgcn_mfma_f32_16x16x32_bf16(af[m], bfr[n], acc[m][n], 0, 0, 0);
        }
        __syncthreads();   // all waves done reading before restage
    }

    // ---- epilogue 2: H = relu(acc + b2) ----
    #pragma unroll
    for (int n = 0; n < 4; n++) {
        int colg = wc + n * 16 + rsel;
        #pragma unroll
        for (int m = 0; m < 4; m++) {
            int rowb = m0 + m * 16 + cr * 4;
            #pragma unroll
            for (int r = 0; r < 4; r++) {
                int row = rowb + r;
                if (row < M) {
                    float v = fmaxf(acc[m][n][r] + sh2[n], 0.f);
                    H[(size_t)row * 256 + colg] = f2b(v);
                }
            }
        }
    }
}

// ---------------- pooling v2: vectorized us8 loads, LDS fixed-order reduction ----------------
__global__ void pool_seg(const unsigned short* __restrict__ h1,
                         const unsigned short* __restrict__ h2,
                         const int* __restrict__ gstart,
                         float* __restrict__ pcat) {
    __shared__ float red1[8][256];
    __shared__ float red2[8][256];
    int g = blockIdx.x;
    int t = threadIdx.x;
    int sub = t >> 5;              // node-group 0..7
    int d8 = (t & 31) * 8;         // element offset within row
    float a1[8], a2[8];
    #pragma unroll
    for (int j = 0; j < 8; j++) { a1[j] = 0.f; a2[j] = 0.f; }
    int s = gstart[g], e = gstart[g + 1];
    for (int n = s + sub; n < e; n += 8) {
        us8 v1 = *reinterpret_cast<const us8*>(&h1[(size_t)n * DIM + d8]);
        us8 v2 = *reinterpret_cast<const us8*>(&h2[(size_t)n * DIM + d8]);
        #pragma unroll
        for (int j = 0; j < 8; j++) {
            a1[j] += b2f((unsigned short)v1[j]);
            a2[j] += b2f((unsigned short)v2[j]);
        }
    }
    #pragma unroll
    for (int j = 0; j < 8; j++) {
        red1[sub][d8 + j] = a1[j];
        red2[sub][d8 + j] = a2[j];
    }
    __syncthreads();
    float o1 = 0.f, o2 = 0.f;
    #pragma unroll
    for (int k = 0; k < 8; k++) { o1 += red1[k][t]; o2 += red2[k][t]; }
    pcat[(size_t)g * 512 + t]       = o1;
    pcat[(size_t)g * 512 + 256 + t] = o2;
}

// ---------------- head stage 1 (split-K): Hpart[z][500][768] = pcat[:, z*128:(z+1)*128] @ W1-slice ----
__global__ void head1(const float* __restrict__ A,    // [500][512]
                      const float* __restrict__ W1,   // [512][768]
                      float* __restrict__ Hpart) {    // [KSPLIT][500][768]
    __shared__ float As[16][65];
    __shared__ float Bs[16][65];
    int t = threadIdx.x;
    int m0 = blockIdx.y * 64;
    int n0 = blockIdx.x * 64;
    int kz = blockIdx.z * (512 / KSPLIT);
    int tx = t & 15, ty = t >> 4;
    float acc[4][4] = {};
    for (int k0 = kz; k0 < kz + 512 / KSPLIT; k0 += 16) {
        #pragma unroll
        for (int i = 0; i < 4; i++) {
            int r = (t >> 4) + i * 16;
            int k = t & 15;
            int gr = m0 + r;
            As[k][r] = (gr < N_GRAPHS) ? A[(size_t)gr * 512 + k0 + k] : 0.f;
        }
        #pragma unroll
        for (int i = 0; i < 4; i++) {
            int k = (t >> 6) + i * 4;
            int n = t & 63;
            Bs[k][n] = W1[(size_t)(k0 + k) * 768 + n0 + n];
        }
        __syncthreads();
        #pragma unroll
        for (int k = 0; k < 16; k++) {
            float a[4], b[4];
            #pragma unroll
            for (int i = 0; i < 4; i++) a[i] = As[k][ty * 4 + i];
            #pragma unroll
            for (int j = 0; j < 4; j++) b[j] = Bs[k][tx * 4 + j];
            #pragma unroll
            for (int i = 0; i < 4; i++)
                #pragma unroll
                for (int j = 0; j < 4; j++)
                    acc[i][j] += a[i] * b[j];
        }
        __syncthreads();
    }
    float* Hz = Hpart + (size_t)blockIdx.z * N_GRAPHS * 768;
    #pragma unroll
    for (int i = 0; i < 4; i++) {
        int gm = m0 + ty * 4 + i;
        if (gm >= N_GRAPHS) continue;
        #pragma unroll
        for (int j = 0; j < 4; j++) {
            int gn = n0 + tx * 4 + j;
            Hz[(size_t)gm * 768 + gn] = acc[i][j];
        }
    }
}

// ---------------- head stage 2: sum partials + bias + relu, GEMV, log_softmax ----------------
__global__ void head2(const float* __restrict__ Hpart, const float* __restrict__ b1,
                      const float* __restrict__ W2, const float* __restrict__ b2,
                      float* __restrict__ out) {
    int g = blockIdx.x;
    int lane = threadIdx.x;   // 64
    float part[N_OUT];
    #pragma unroll
    for (int o = 0; o < N_OUT; o++) part[o] = 0.f;
    for (int k = lane; k < 768; k += 64) {
        float hv = b1[k];
        #pragma unroll
        for (int z = 0; z < KSPLIT; z++)
            hv += Hpart[((size_t)z * N_GRAPHS + g) * 768 + k];
        hv = fmaxf(hv, 0.f);
        #pragma unroll
        for (int o = 0; o < N_OUT; o++) part[o] += hv * W2[(size_t)k * N_OUT + o];
    }
    #pragma unroll
    for (int o = 0; o < N_OUT; o++) {
        #pragma unroll
        for (int off = 32; off > 0; off >>= 1)
            part[o] += __shfl_down(part[o], off, 64);
    }
    if (lane == 0) {
        float logits[N_OUT];
        float mx = -1e30f;
        #pragma unroll
        for (int o = 0; o < N_OUT; o++) { logits[o] = part[o] + b2[o]; mx = fmaxf(mx, logits[o]); }
        float ssum = 0.f;
        #pragma unroll
        for (int o = 0; o < N_OUT; o++) ssum += expf(logits[o] - mx);
        float lse = logf(ssum);
        #pragma unroll
        for (int o = 0; o < N_OUT; o++)
            out[(size_t)g * N_OUT + o] = logits[o] - mx - lse;
    }
}

extern "C" void kernel_launch(void* const* d_in, const int* in_sizes, int n_in,
                              void* d_out, int out_size, void* d_ws, size_t ws_size,
                              hipStream_t stream) {
    const float* x     = (const float*)d_in[0];
    const int*   ei    = (const int*)d_in[1];
    const int*   batch = (const int*)d_in[2];
    const float* W1a = (const float*)d_in[3];
    const float* b1a = (const float*)d_in[4];
    const float* g1a = (const float*)d_in[5];
    const float* be1a= (const float*)d_in[6];
    const float* m1a = (const float*)d_in[7];
    const float* v1a = (const float*)d_in[8];
    const float* W2a = (const float*)d_in[9];
    const float* b2a = (const float*)d_in[10];
    const float* W1b = (const float*)d_in[11];
    const float* b1b = (const float*)d_in[12];
    const float* g1b = (const float*)d_in[13];
    const float* be1b= (const float*)d_in[14];
    const float* m1b = (const float*)d_in[15];
    const float* v1b = (const float*)d_in[16];
    const float* W2b = (const float*)d_in[17];
    const float* b2b = (const float*)d_in[18];
    const float* lin1_W = (const float*)d_in[19];
    const float* lin1_b = (const float*)d_in[20];
    const float* lin2_W = (const float*)d_in[21];
    const float* lin2_b = (const float*)d_in[22];

    const size_t NBUF = (size_t)MPAD * DIM;
    char* ws = (char*)d_ws;
    unsigned short* agg  = (unsigned short*)ws;            ws += NBUF * 2;
    unsigned short* h1   = (unsigned short*)ws;            ws += NBUF * 2;
    unsigned short* h2   = (unsigned short*)ws;            ws += NBUF * 2;
    unsigned short* x_bf = (unsigned short*)ws;            ws += (size_t)N_NODES * DIM * 2;
    unsigned short* Wt   = (unsigned short*)ws;            ws += 4 * 65536 * 2;
    float* ss    = (float*)ws;                             ws += 4 * 256 * 4;   // 2x(scale,shift)
    float* pcat  = (float*)ws;                             ws += (size_t)N_GRAPHS * 512 * 4;
    float* Hpart = (float*)ws;                             ws += (size_t)KSPLIT * N_GRAPHS * 768 * 4;
    int* deg     = (int*)ws;                               ws += (size_t)N_NODES * 4;
    int* cursor  = (int*)ws;                               ws += (size_t)N_NODES * 4;
    int* rowptr  = (int*)ws;                               ws += (size_t)(N_NODES + 1) * 4;
    int* bsum    = (int*)ws;                               ws += 64 * 4;
    int* col     = (int*)ws;                               ws += (size_t)N_EDGES * 4;
    int* gstart  = (int*)ws;

    const int* srcE = ei;
    const int* dstE = ei + N_EDGES;

    const int nscan = (N_NODES + SCAN_BS - 1) / SCAN_BS;

    // ---- CSR build (by dst), shared by both layers; sorted for determinism ----
    zero_i<<<(N_NODES + 255) / 256, 256, 0, stream>>>(deg, N_NODES);
    hist_dst<<<(N_EDGES + 255) / 256, 256, 0, stream>>>(dstE, deg);
    scan_phase1<<<nscan, SCAN_BS, 0, stream>>>(deg, rowptr, bsum, N_NODES);
    scan_phase2<<<1, 64, 0, stream>>>(bsum, nscan);
    scan_phase3<<<nscan, SCAN_BS, 0, stream>>>(rowptr, cursor, bsum, N_NODES);
    fill_csr<<<(N_EDGES + 255) / 256, 256, 0, stream>>>(srcE, dstE, cursor, col);
    sort_csr<<<(N_NODES + 3) / 4, 256, 0, stream>>>(rowptr, col);
    graph_starts<<<2, 256, 0, stream>>>(batch, gstart);

    // ---- precompute ----
    conv_x<<<(N_NODES * DIM / 4 + 255) / 256, 256, 0, stream>>>(
        (const float4*)x, (ushort4*)x_bf, N_NODES * DIM / 4);
    dim3 wt_grid(256, 4);
    conv_wt4<<<wt_grid, 256, 0, stream>>>(W1a, W2a, W1b, W2b, Wt);
    make_ss<<<1, 256, 0, stream>>>(b1a, g1a, be1a, m1a, v1a, ss + 0 * 512, ss + 0 * 512 + 256);
    make_ss<<<1, 256, 0, stream>>>(b1b, g1b, be1b, m1b, v1b, ss + 1 * 512, ss + 1 * 512 + 256);

    // ---- layer 1 ----
    gather_bf<<<(N_NODES + 3) / 4, 256, 0, stream>>>(x_bf, col, rowptr, agg);
    fused_mlp<<<MPAD / 64, 256, 0, stream>>>(agg, Wt + 0 * 65536, Wt + 1 * 65536,
                                             ss + 0 * 512, ss + 0 * 512 + 256, b2a, h1, N_NODES);

    // ---- layer 2 ----
    gather_bf<<<(N_NODES + 3) / 4, 256, 0, stream>>>(h1, col, rowptr, agg);
    fused_mlp<<<MPAD / 64, 256, 0, stream>>>(agg, Wt + 2 * 65536, Wt + 3 * 65536,
                                             ss + 1 * 512, ss + 1 * 512 + 256, b2b, h2, N_NODES);

    // ---- pooling + head ----
    pool_seg<<<N_GRAPHS, 256, 0, stream>>>(h1, h2, gstart, pcat);
    dim3 h1grid(12, 8, KSPLIT);
    head1<<<h1grid, 256, 0, stream>>>(pcat, lin1_W, Hpart);
    head2<<<N_GRAPHS, 64, 0, stream>>>(Hpart, lin1_b, lin2_W, lin2_b, (float*)d_out);
}

// Round 17
// 350.925 us; speedup vs baseline: 1.6197x; 1.0299x over previous
//
#include <hip/hip_runtime.h>

#define N_NODES 50000
#define MPAD 50176            // 784*64, node-buffer row padding for GEMM staging
#define N_EDGES 800000
#define DIM 256
#define N_GRAPHS 500
#define GPAD 512              // padded graph rows for head1 MFMA staging
#define N_OUT 10
#define BN_EPS 1e-5f
#define SCAN_BS 1024
#define SORT_CAP 96           // max degree handled by sort (Poisson(16): P(deg>96) ~ 0)

typedef unsigned int u32;
typedef short bf16x8 __attribute__((ext_vector_type(8)));
typedef unsigned short us8 __attribute__((ext_vector_type(8)));
typedef float f32x4 __attribute__((ext_vector_type(4)));

typedef __attribute__((address_space(1))) const unsigned int gas_u32;
typedef __attribute__((address_space(3))) unsigned int las_u32;

__device__ inline void g2l16(const void* g, void* l) {
    // async global->LDS, 16 bytes per lane; LDS dest = wave-uniform base + lane*16
    __builtin_amdgcn_global_load_lds((gas_u32*)g, (las_u32*)l, 16, 0, 0);
}

__device__ inline float b2f(unsigned short u) {
    union { u32 i; float f; } c; c.i = ((u32)u) << 16; return c.f;
}
__device__ inline unsigned short f2b(float f) {   // round-to-nearest-even
    u32 x = __builtin_bit_cast(u32, f);
    return (unsigned short)((x + 0x7FFFu + ((x >> 16) & 1u)) >> 16);
}

// swizzled byte address into the 64x256-bf16 mid LDS tile (row stride 512B = 32 slots):
// slot ^= row&31 is bijective per row and de-conflicts stride-512B column reads.
__device__ inline int mid_addr(int row, int col) {
    return row * 512 + ((((col >> 3) ^ (row & 31)) << 4) | ((col & 7) << 1));
}

// ---------------- CSR build ----------------
__global__ void zero_i(int* __restrict__ p, int n) {
    int i = blockIdx.x * blockDim.x + threadIdx.x;
    if (i < n) p[i] = 0;
}
__global__ void hist_dst(const int* __restrict__ dst, int* __restrict__ deg) {
    int e = blockIdx.x * blockDim.x + threadIdx.x;
    if (e < N_EDGES) atomicAdd(&deg[dst[e]], 1);
}
__global__ void scan_phase1(const int* __restrict__ deg, int* __restrict__ rowptr,
                            int* __restrict__ bsum, int n) {
    __shared__ int sh[SCAN_BS];
    int i = blockIdx.x * SCAN_BS + threadIdx.x;
    int v = (i < n) ? deg[i] : 0;
    sh[threadIdx.x] = v;
    __syncthreads();
    for (int off = 1; off < SCAN_BS; off <<= 1) {
        int t = (threadIdx.x >= off) ? sh[threadIdx.x - off] : 0;
        __syncthreads();
        sh[threadIdx.x] += t;
        __syncthreads();
    }
    if (i < n) rowptr[i] = sh[threadIdx.x] - v;
    if (threadIdx.x == SCAN_BS - 1) bsum[blockIdx.x] = sh[threadIdx.x];
}
__global__ void scan_phase2(int* __restrict__ bsum, int nb) {
    if (threadIdx.x == 0 && blockIdx.x == 0) {
        int run = 0;
        for (int b = 0; b < nb; b++) { int v = bsum[b]; bsum[b] = run; run += v; }
    }
}
__global__ void scan_phase3(int* __restrict__ rowptr, int* __restrict__ cursor,
                            const int* __restrict__ bsum, int n) {
    int i = blockIdx.x * SCAN_BS + threadIdx.x;
    if (i < n) {
        int v = rowptr[i] + bsum[blockIdx.x];
        rowptr[i] = v;
        cursor[i] = v;
    }
    if (i == 0) rowptr[n] = N_EDGES;
}
__global__ void fill_csr(const int* __restrict__ src, const int* __restrict__ dst,
                         int* __restrict__ cursor, int* __restrict__ col) {
    int e = blockIdx.x * blockDim.x + threadIdx.x;
    if (e < N_EDGES) {
        int p = atomicAdd(&cursor[dst[e]], 1);
        col[p] = src[e];
    }
}
// canonicalize neighbor order (atomic fill order is nondeterministic -> f32 sum order
// would vary call-to-call; harness requires identical output every call).
__global__ void sort_csr(const int* __restrict__ rowptr, int* __restrict__ col) {
    __shared__ int buf[4][SORT_CAP];
    int node = blockIdx.x * 4 + (threadIdx.x >> 6);
    if (node >= N_NODES) return;
    int lane = threadIdx.x & 63;
    int w = threadIdx.x >> 6;
    int s = rowptr[node], e = rowptr[node + 1];
    int L = e - s;
    if (L <= 1 || L > SORT_CAP) return;
    for (int i = lane; i < L; i += 64) buf[w][i] = col[s + i];
    asm volatile("s_waitcnt lgkmcnt(0) vmcnt(0)" ::: "memory");
    for (int pass = 0; pass < L; pass++) {
        int base = 2 * lane + (pass & 1);
        if (base + 1 < L) {
            int a = buf[w][base], b = buf[w][base + 1];
            if (a > b) { buf[w][base] = b; buf[w][base + 1] = a; }
        }
        asm volatile("s_waitcnt lgkmcnt(0)" ::: "memory");
    }
    for (int i = lane; i < L; i += 64) col[s + i] = buf[w][i];
}
__global__ void graph_starts(const int* __restrict__ batch, int* __restrict__ gstart) {
    int g = blockIdx.x * blockDim.x + threadIdx.x;
    if (g > N_GRAPHS) return;
    if (g == N_GRAPHS) { gstart[g] = N_NODES; return; }
    int lo = 0, hi = N_NODES;
    while (lo < hi) { int mid = (lo + hi) >> 1; if (batch[mid] < g) lo = mid + 1; else hi = mid; }
    gstart[g] = lo;
}

// ---------------- conversions ----------------
__global__ void conv_x(const float4* __restrict__ in, ushort4* __restrict__ out, int n4) {
    int i = blockIdx.x * blockDim.x + threadIdx.x;
    if (i < n4) {
        float4 v = in[i];
        ushort4 o; o.x = f2b(v.x); o.y = f2b(v.y); o.z = f2b(v.z); o.w = f2b(v.w);
        out[i] = o;
    }
}
// Wt[mat][n][k] = bf16(W[mat][k][n])
__global__ void conv_wt4(const float* __restrict__ W0, const float* __restrict__ W1,
                         const float* __restrict__ W2, const float* __restrict__ W3,
                         unsigned short* __restrict__ Wt) {
    int mat = blockIdx.y;
    const float* W = (mat == 0) ? W0 : (mat == 1) ? W1 : (mat == 2) ? W2 : W3;
    int n = blockIdx.x;
    int k = threadIdx.x;
    Wt[((size_t)mat << 16) + (size_t)n * 256 + k] = f2b(W[(size_t)k * 256 + n]);
}
// W1h[n][k] = bf16(lin1_W[k][n]); n in [0,768), k in [0,512)
__global__ void conv_w1h(const float* __restrict__ W, unsigned short* __restrict__ Wh) {
    int n = blockIdx.x;
    int k = threadIdx.x;          // 256 threads, 2 k each
    Wh[(size_t)n * 512 + k]       = f2b(W[(size_t)k * 768 + n]);
    Wh[(size_t)n * 512 + 256 + k] = f2b(W[(size_t)(256 + k) * 768 + n]);
}
__global__ void make_ss(const float* __restrict__ bias, const float* __restrict__ gamma,
                        const float* __restrict__ beta, const float* __restrict__ mean,
                        const float* __restrict__ var, float* __restrict__ scale,
                        float* __restrict__ shift) {
    int i = threadIdx.x;
    float s = gamma[i] * rsqrtf(var[i] + BN_EPS);
    scale[i] = s;
    shift[i] = (bias[i] - mean[i]) * s + beta[i];
}

// ---------------- gather aggregate (bf16): out[i] = feat[i] + sum_{j in N(i)} feat[j] ----------------
// one wave per node; two 32-lane halves own alternate edges; 16 B/lane loads; x4 unroll (8 streams/wave).
__global__ void gather_bf(const unsigned short* __restrict__ feat,
                          const int* __restrict__ col,
                          const int* __restrict__ rowptr,
                          unsigned short* __restrict__ out) {
    int node = blockIdx.x * 4 + (threadIdx.x >> 6);
    if (node >= N_NODES) return;
    int lane = threadIdx.x & 63;
    int half = lane >> 5;
    int d8 = (lane & 31) * 8;          // 8 bf16 = 16 B per lane
    float acc[8];
    #pragma unroll
    for (int j = 0; j < 8; j++) acc[j] = 0.f;
    if (half == 0) {
        us8 own = *reinterpret_cast<const us8*>(&feat[(size_t)node * DIM + d8]);
        #pragma unroll
        for (int j = 0; j < 8; j++) acc[j] = b2f((unsigned short)own[j]);
    }
    int s = rowptr[node], e = rowptr[node + 1];
    int i = s + half;
    for (; i + 6 < e; i += 8) {        // 4 edges per half per iter
        int n0 = col[i], n1 = col[i + 2], n2 = col[i + 4], n3 = col[i + 6];
        us8 v0 = *reinterpret_cast<const us8*>(&feat[(size_t)n0 * DIM + d8]);
        us8 v1 = *reinterpret_cast<const us8*>(&feat[(size_t)n1 * DIM + d8]);
        us8 v2 = *reinterpret_cast<const us8*>(&feat[(size_t)n2 * DIM + d8]);
        us8 v3 = *reinterpret_cast<const us8*>(&feat[(size_t)n3 * DIM + d8]);
        #pragma unroll
        for (int j = 0; j < 8; j++)
            acc[j] += (b2f((unsigned short)v0[j]) + b2f((unsigned short)v1[j]))
                    + (b2f((unsigned short)v2[j]) + b2f((unsigned short)v3[j]));
    }
    for (; i < e; i += 2) {
        int n0 = col[i];
        us8 v0 = *reinterpret_cast<const us8*>(&feat[(size_t)n0 * DIM + d8]);
        #pragma unroll
        for (int j = 0; j < 8; j++) acc[j] += b2f((unsigned short)v0[j]);
    }
    #pragma unroll
    for (int j = 0; j < 8; j++) acc[j] += __shfl_xor(acc[j], 32, 64);
    if (half == 0) {
        us8 o;
        #pragma unroll
        for (int j = 0; j < 8; j++) o[j] = (short)f2b(acc[j]);
        *reinterpret_cast<us8*>(&out[(size_t)node * DIM + d8]) = o;
    }
}

// ---------------- fused GIN MLP v3:  H = relu(relu(bn(A@W1)) @ W2 + b2) ------
// 256 threads, 64-row tile, 4 waves as 1M x 4N (wave 64x64), BK=64, K=256 -> 4 steps/phase.
// Single-buffered, full-drain __syncthreads; A/B LDS XOR-swizzled via pre-swizzled source.
__global__ __launch_bounds__(256, 2)
void fused_mlp(const unsigned short* __restrict__ A,
               const unsigned short* __restrict__ W1t,   // [256][256], W1t[n][k]
               const unsigned short* __restrict__ W2t,   // [256][256], W2t[n][k]
               const float* __restrict__ scale1,
               const float* __restrict__ shift1,
               const float* __restrict__ shift2,         // b2
               unsigned short* __restrict__ H, int M) {
    __shared__ __align__(16) unsigned short Asb[64 * 64];    // 8 KB  (64 rows x 64 k)
    __shared__ __align__(16) unsigned short Bsb[256 * 64];   // 32 KB (256 n x 64 k)
    __shared__ __align__(16) unsigned short midb[64 * 256];  // 32 KB, mid_addr swizzle

    int t = threadIdx.x;
    int wave = t >> 6, lane = t & 63;
    int m0 = blockIdx.x * 64;
    int wc = wave * 64;
    int rsel = lane & 15;
    int kgrp = lane >> 4;            // 16B chunk-in-subtile 0..3
    int cr = lane >> 4;

    float s1[4], sh1[4], sh2[4];
    #pragma unroll
    for (int n = 0; n < 4; n++) {
        int colg = wc + n * 16 + rsel;
        s1[n]  = scale1[colg];
        sh1[n] = shift1[colg];
        sh2[n] = shift2[colg];
    }

    f32x4 acc[4][4];
    #pragma unroll
    for (int m = 0; m < 4; m++)
        #pragma unroll
        for (int n = 0; n < 4; n++)
            acc[m][n] = (f32x4){0.f, 0.f, 0.f, 0.f};

    int arow0 = t >> 3, achk0 = t & 7;
    int arow1 = (256 + t) >> 3, achk1 = t & 7;
    const char* Abase = (const char*)A + (size_t)m0 * 512;

    // ---- phase 1: acc = A @ W1 ----
    for (int ks = 0; ks < 4; ks++) {
        size_t ko = (size_t)ks * 128;
        g2l16(Abase + (size_t)arow0 * 512 + ko + ((achk0 ^ (arow0 & 7)) << 4),
              (char*)Asb + (size_t)t * 16);
        g2l16(Abase + (size_t)arow1 * 512 + ko + ((achk1 ^ (arow1 & 7)) << 4),
              (char*)Asb + (size_t)(256 + t) * 16);
        #pragma unroll
        for (int i = 0; i < 8; i++) {
            int s = i * 256 + t;
            int brow = s >> 3, bchk = s & 7;
            g2l16((const char*)W1t + (size_t)brow * 512 + ko + ((bchk ^ (brow & 7)) << 4),
                  (char*)Bsb + (size_t)s * 16);
        }
        __syncthreads();

        #pragma unroll
        for (int ksub = 0; ksub < 2; ksub++) {
            bf16x8 af[4], bfr[4];
            int kchunk = ksub * 4 + kgrp;
            #pragma unroll
            for (int m = 0; m < 4; m++) {
                int row = m * 16 + rsel;
                af[m] = *(const bf16x8*)((const char*)Asb + (size_t)row * 128
                                         + ((kchunk ^ (row & 7)) << 4));
            }
            #pragma unroll
            for (int n = 0; n < 4; n++) {
                int row = wc + n * 16 + rsel;
                bfr[n] = *(const bf16x8*)((const char*)Bsb + (size_t)row * 128
                                          + ((kchunk ^ (row & 7)) << 4));
            }
            #pragma unroll
            for (int m = 0; m < 4; m++)
                #pragma unroll
                for (int n = 0; n < 4; n++)
                    acc[m][n] = __builtin_amdgcn_mfma_f32_16x16x32_bf16(af[m], bfr[n], acc[m][n], 0, 0, 0);
        }
        __syncthreads();
    }

    // ---- epilogue 1: mid = relu(acc*scale1 + shift1) -> bf16 -> swizzled LDS; reset acc ----
    #pragma unroll
    for (int n = 0; n < 4; n++) {
        int colg = wc + n * 16 + rsel;
        #pragma unroll
        for (int m = 0; m < 4; m++) {
            int rowb = m * 16 + cr * 4;
            #pragma unroll
            for (int r = 0; r < 4; r++) {
                float v = fmaxf(acc[m][n][r] * s1[n] + sh1[n], 0.f);
                *(unsigned short*)((char*)midb + mid_addr(rowb + r, colg)) = f2b(v);
                acc[m][n][r] = 0.f;
            }
        }
    }

    // ---- phase 2: acc = mid @ W2 ----
    for (int ks = 0; ks < 4; ks++) {
        size_t ko = (size_t)ks * 128;
        #pragma unroll
        for (int i = 0; i < 8; i++) {
            int s = i * 256 + t;
            int brow = s >> 3, bchk = s & 7;
            g2l16((const char*)W2t + (size_t)brow * 512 + ko + ((bchk ^ (brow & 7)) << 4),
                  (char*)Bsb + (size_t)s * 16);
        }
        __syncthreads();

        #pragma unroll
        for (int ksub = 0; ksub < 2; ksub++) {
            bf16x8 af[4], bfr[4];
            int kchunk = ksub * 4 + kgrp;
            int kcol = ks * 64 + ksub * 32 + kgrp * 8;
            #pragma unroll
            for (int m = 0; m < 4; m++)
                af[m] = *(const bf16x8*)((const char*)midb + mid_addr(m * 16 + rsel, kcol));
            #pragma unroll
            for (int n = 0; n < 4; n++) {
                int row = wc + n * 16 + rsel;
                bfr[n] = *(const bf16x8*)((const char*)Bsb + (size_t)row * 128
                                          + ((kchunk ^ (row & 7)) << 4));
            }
            #pragma unroll
            for (int m = 0; m < 4; m++)
                #pragma unroll
                for (int n = 0; n < 4; n++)
                    acc[m][n] = __builtin_amdgcn_mfma_f32_16x16x32_bf16(af[m], bfr[n], acc[m][n], 0, 0, 0);
        }
        __syncthreads();
    }

    // ---- epilogue 2: H = relu(acc + b2) ----
    #pragma unroll
    for (int n = 0; n < 4; n++) {
        int colg = wc + n * 16 + rsel;
        #pragma unroll
        for (int m = 0; m < 4; m++) {
            int rowb = m0 + m * 16 + cr * 4;
            #pragma unroll
            for (int r = 0; r < 4; r++) {
                int row = rowb + r;
                if (row < M) {
                    float v = fmaxf(acc[m][n][r] + sh2[n], 0.f);
                    H[(size_t)row * 256 + colg] = f2b(v);
                }
            }
        }
    }
}

// ---------------- pooling v3: vectorized us8 loads, bf16 pcat output ----------------
__global__ void pool_seg(const unsigned short* __restrict__ h1,
                         const unsigned short* __restrict__ h2,
                         const int* __restrict__ gstart,
                         unsigned short* __restrict__ pcat) {    // [GPAD][512] bf16
    __shared__ float red1[8][256];
    __shared__ float red2[8][256];
    int g = blockIdx.x;
    int t = threadIdx.x;
    int sub = t >> 5;
    int d8 = (t & 31) * 8;
    float a1[8], a2[8];
    #pragma unroll
    for (int j = 0; j < 8; j++) { a1[j] = 0.f; a2[j] = 0.f; }
    int s = gstart[g], e = gstart[g + 1];
    for (int n = s + sub; n < e; n += 8) {
        us8 v1 = *reinterpret_cast<const us8*>(&h1[(size_t)n * DIM + d8]);
        us8 v2 = *reinterpret_cast<const us8*>(&h2[(size_t)n * DIM + d8]);
        #pragma unroll
        for (int j = 0; j < 8; j++) {
            a1[j] += b2f((unsigned short)v1[j]);
            a2[j] += b2f((unsigned short)v2[j]);
        }
    }
    #pragma unroll
    for (int j = 0; j < 8; j++) {
        red1[sub][d8 + j] = a1[j];
        red2[sub][d8 + j] = a2[j];
    }
    __syncthreads();
    float o1 = 0.f, o2 = 0.f;
    #pragma unroll
    for (int k = 0; k < 8; k++) { o1 += red1[k][t]; o2 += red2[k][t]; }
    pcat[(size_t)g * 512 + t]       = f2b(o1);
    pcat[(size_t)g * 512 + 256 + t] = f2b(o2);
}

// ---------------- head stage 1 (MFMA): Hf[500 x 768] = relu(pcat @ lin1_W + b1) ----------------
// 256 threads, 4 waves as 1M x 4N, block tile 64(M) x 256(N); grid (3 nblk, 8 mblk).
// K=512, BK=64 -> 8 steps, single-buffered, XOR-swizzled LDS (same scheme as fused_mlp).
__global__ __launch_bounds__(256)
void head1_mfma(const unsigned short* __restrict__ A,    // [GPAD][512] bf16 (pcat)
                const unsigned short* __restrict__ Wh,   // [768][512] bf16, Wh[n][k]
                const float* __restrict__ b1,
                float* __restrict__ Hf) {                // [GPAD][768] f32
    __shared__ __align__(16) unsigned short Asb[64 * 64];    // 8 KB
    __shared__ __align__(16) unsigned short Bsb[256 * 64];   // 32 KB

    int t = threadIdx.x;
    int wave = t >> 6, lane = t & 63;
    int n0 = blockIdx.x * 256;
    int m0 = blockIdx.y * 64;
    int wc = wave * 64;
    int rsel = lane & 15;
    int kgrp = lane >> 4;
    int cr = lane >> 4;

    float bb[4];
    #pragma unroll
    for (int n = 0; n < 4; n++) bb[n] = b1[n0 + wc + n * 16 + rsel];

    f32x4 acc[4][4];
    #pragma unroll
    for (int m = 0; m < 4; m++)
        #pragma unroll
        for (int n = 0; n < 4; n++)
            acc[m][n] = (f32x4){0.f, 0.f, 0.f, 0.f};

    int arow0 = t >> 3, achk0 = t & 7;
    int arow1 = (256 + t) >> 3, achk1 = t & 7;
    const char* Abase = (const char*)A + (size_t)m0 * 1024;   // row stride 512 bf16 = 1024 B

    for (int ks = 0; ks < 8; ks++) {
        size_t ko = (size_t)ks * 128;   // 64 bf16 per step
        g2l16(Abase + (size_t)arow0 * 1024 + ko + ((achk0 ^ (arow0 & 7)) << 4),
              (char*)Asb + (size_t)t * 16);
        g2l16(Abase + (size_t)arow1 * 1024 + ko + ((achk1 ^ (arow1 & 7)) << 4),
              (char*)Asb + (size_t)(256 + t) * 16);
        #pragma unroll
        for (int i = 0; i < 8; i++) {
            int s = i * 256 + t;
            int brow = s >> 3, bchk = s & 7;
            g2l16((const char*)Wh + (size_t)(n0 + brow) * 1024 + ko + ((bchk ^ (brow & 7)) << 4),
                  (char*)Bsb + (size_t)s * 16);
        }
        __syncthreads();

        #pragma unroll
        for (int ksub = 0; ksub < 2; ksub++) {
            bf16x8 af[4], bfr[4];
            int kchunk = ksub * 4 + kgrp;
            #pragma unroll
            for (int m = 0; m < 4; m++) {
                int row = m * 16 + rsel;
                af[m] = *(const bf16x8*)((const char*)Asb + (size_t)row * 128
                                         + ((kchunk ^ (row & 7)) << 4));
            }
            #pragma unroll
            for (int n = 0; n < 4; n++) {
                int row = wc + n * 16 + rsel;
                bfr[n] = *(const bf16x8*)((const char*)Bsb + (size_t)row * 128
                                          + ((kchunk ^ (row & 7)) << 4));
            }
            #pragma unroll
            for (int m = 0; m < 4; m++)
                #pragma unroll
                for (int n = 0; n < 4; n++)
                    acc[m][n] = __builtin_amdgcn_mfma_f32_16x16x32_bf16(af[m], bfr[n], acc[m][n], 0, 0, 0);
        }
        __syncthreads();
    }

    // epilogue: Hf = relu(acc + b1), f32 store; C/D map col=lane&15, row=(lane>>4)*4+reg
    #pragma unroll
    for (int n = 0; n < 4; n++) {
        int colg = n0 + wc + n * 16 + rsel;
        #pragma unroll
        for (int m = 0; m < 4; m++) {
            int rowb = m0 + m * 16 + cr * 4;
            #pragma unroll
            for (int r = 0; r < 4; r++) {
                int row = rowb + r;
                if (row < N_GRAPHS)
                    Hf[(size_t)row * 768 + colg] = fmaxf(acc[m][n][r] + bb[n], 0.f);
            }
        }
    }
}

// ---------------- head stage 2: GEMV + log_softmax (bias/relu already in head1) ----------------
__global__ void head2(const float* __restrict__ Hf, const float* __restrict__ W2,
                      const float* __restrict__ b2, float* __restrict__ out) {
    int g = blockIdx.x;
    int lane = threadIdx.x;   // 64
    float part[N_OUT];
    #pragma unroll
    for (int o = 0; o < N_OUT; o++) part[o] = 0.f;
    for (int k = lane; k < 768; k += 64) {
        float hv = Hf[(size_t)g * 768 + k];
        #pragma unroll
        for (int o = 0; o < N_OUT; o++) part[o] += hv * W2[(size_t)k * N_OUT + o];
    }
    #pragma unroll
    for (int o = 0; o < N_OUT; o++) {
        #pragma unroll
        for (int off = 32; off > 0; off >>= 1)
            part[o] += __shfl_down(part[o], off, 64);
    }
    if (lane == 0) {
        float logits[N_OUT];
        float mx = -1e30f;
        #pragma unroll
        for (int o = 0; o < N_OUT; o++) { logits[o] = part[o] + b2[o]; mx = fmaxf(mx, logits[o]); }
        float ssum = 0.f;
        #pragma unroll
        for (int o = 0; o < N_OUT; o++) ssum += expf(logits[o] - mx);
        float lse = logf(ssum);
        #pragma unroll
        for (int o = 0; o < N_OUT; o++)
            out[(size_t)g * N_OUT + o] = logits[o] - mx - lse;
    }
}

extern "C" void kernel_launch(void* const* d_in, const int* in_sizes, int n_in,
                              void* d_out, int out_size, void* d_ws, size_t ws_size,
                              hipStream_t stream) {
    const float* x     = (const float*)d_in[0];
    const int*   ei    = (const int*)d_in[1];
    const int*   batch = (const int*)d_in[2];
    const float* W1a = (const float*)d_in[3];
    const float* b1a = (const float*)d_in[4];
    const float* g1a = (const float*)d_in[5];
    const float* be1a= (const float*)d_in[6];
    const float* m1a = (const float*)d_in[7];
    const float* v1a = (const float*)d_in[8];
    const float* W2a = (const float*)d_in[9];
    const float* b2a = (const float*)d_in[10];
    const float* W1b = (const float*)d_in[11];
    const float* b1b = (const float*)d_in[12];
    const float* g1b = (const float*)d_in[13];
    const float* be1b= (const float*)d_in[14];
    const float* m1b = (const float*)d_in[15];
    const float* v1b = (const float*)d_in[16];
    const float* W2b = (const float*)d_in[17];
    const float* b2b = (const float*)d_in[18];
    const float* lin1_W = (const float*)d_in[19];
    const float* lin1_b = (const float*)d_in[20];
    const float* lin2_W = (const float*)d_in[21];
    const float* lin2_b = (const float*)d_in[22];

    const size_t NBUF = (size_t)MPAD * DIM;
    char* ws = (char*)d_ws;
    unsigned short* agg  = (unsigned short*)ws;            ws += NBUF * 2;
    unsigned short* h1   = (unsigned short*)ws;            ws += NBUF * 2;
    unsigned short* h2   = (unsigned short*)ws;            ws += NBUF * 2;
    unsigned short* x_bf = (unsigned short*)ws;            ws += (size_t)N_NODES * DIM * 2;
    unsigned short* Wt   = (unsigned short*)ws;            ws += 4 * 65536 * 2;
    unsigned short* W1h  = (unsigned short*)ws;            ws += (size_t)768 * 512 * 2;
    float* ss    = (float*)ws;                             ws += 4 * 256 * 4;   // 2x(scale,shift)
    unsigned short* pcat = (unsigned short*)ws;            ws += (size_t)GPAD * 512 * 2;
    float* Hf    = (float*)ws;                             ws += (size_t)GPAD * 768 * 4;
    int* deg     = (int*)ws;                               ws += (size_t)N_NODES * 4;
    int* cursor  = (int*)ws;                               ws += (size_t)N_NODES * 4;
    int* rowptr  = (int*)ws;                               ws += (size_t)(N_NODES + 1) * 4;
    int* bsum    = (int*)ws;                               ws += 64 * 4;
    int* col     = (int*)ws;                               ws += (size_t)N_EDGES * 4;
    int* gstart  = (int*)ws;

    const int* srcE = ei;
    const int* dstE = ei + N_EDGES;

    const int nscan = (N_NODES + SCAN_BS - 1) / SCAN_BS;

    // ---- CSR build (by dst), shared by both layers; sorted for determinism ----
    zero_i<<<(N_NODES + 255) / 256, 256, 0, stream>>>(deg, N_NODES);
    hist_dst<<<(N_EDGES + 255) / 256, 256, 0, stream>>>(dstE, deg);
    scan_phase1<<<nscan, SCAN_BS, 0, stream>>>(deg, rowptr, bsum, N_NODES);
    scan_phase2<<<1, 64, 0, stream>>>(bsum, nscan);
    scan_phase3<<<nscan, SCAN_BS, 0, stream>>>(rowptr, cursor, bsum, N_NODES);
    fill_csr<<<(N_EDGES + 255) / 256, 256, 0, stream>>>(srcE, dstE, cursor, col);
    sort_csr<<<(N_NODES + 3) / 4, 256, 0, stream>>>(rowptr, col);
    graph_starts<<<2, 256, 0, stream>>>(batch, gstart);

    // ---- precompute ----
    conv_x<<<(N_NODES * DIM / 4 + 255) / 256, 256, 0, stream>>>(
        (const float4*)x, (ushort4*)x_bf, N_NODES * DIM / 4);
    dim3 wt_grid(256, 4);
    conv_wt4<<<wt_grid, 256, 0, stream>>>(W1a, W2a, W1b, W2b, Wt);
    conv_w1h<<<768, 256, 0, stream>>>(lin1_W, W1h);
    make_ss<<<1, 256, 0, stream>>>(b1a, g1a, be1a, m1a, v1a, ss + 0 * 512, ss + 0 * 512 + 256);
    make_ss<<<1, 256, 0, stream>>>(b1b, g1b, be1b, m1b, v1b, ss + 1 * 512, ss + 1 * 512 + 256);

    // ---- layer 1 ----
    gather_bf<<<(N_NODES + 3) / 4, 256, 0, stream>>>(x_bf, col, rowptr, agg);
    fused_mlp<<<MPAD / 64, 256, 0, stream>>>(agg, Wt + 0 * 65536, Wt + 1 * 65536,
                                             ss + 0 * 512, ss + 0 * 512 + 256, b2a, h1, N_NODES);

    // ---- layer 2 ----
    gather_bf<<<(N_NODES + 3) / 4, 256, 0, stream>>>(h1, col, rowptr, agg);
    fused_mlp<<<MPAD / 64, 256, 0, stream>>>(agg, Wt + 2 * 65536, Wt + 3 * 65536,
                                             ss + 1 * 512, ss + 1 * 512 + 256, b2b, h2, N_NODES);

    // ---- pooling + head ----
    pool_seg<<<N_GRAPHS, 256, 0, stream>>>(h1, h2, gstart, pcat);
    dim3 h1grid(3, 8);
    head1_mfma<<<h1grid, 256, 0, stream>>>(pcat, W1h, lin1_b, Hf);
    head2<<<N_GRAPHS, 64, 0, stream>>>(Hf, lin2_W, lin2_b, (float*)d_out);
}

// Round 18
// 341.952 us; speedup vs baseline: 1.6622x; 1.0262x over previous
//
#include <hip/hip_runtime.h>

#define N_NODES 50000
#define MPAD 50176            // 784*64, node-buffer row padding for GEMM staging
#define N_EDGES 800000
#define DIM 256
#define N_GRAPHS 500
#define GPAD 512              // padded graph rows for head1 MFMA staging
#define N_OUT 10
#define BN_EPS 1e-5f
#define SCAN_BS 1024
#define SORT_CAP 96           // max degree handled by sort (Poisson(16): P(deg>96) ~ 0)

typedef unsigned int u32;
typedef short bf16x8 __attribute__((ext_vector_type(8)));
typedef unsigned short us8 __attribute__((ext_vector_type(8)));
typedef float f32x4 __attribute__((ext_vector_type(4)));

typedef __attribute__((address_space(1))) const unsigned int gas_u32;
typedef __attribute__((address_space(3))) unsigned int las_u32;

__device__ inline void g2l16(const void* g, void* l) {
    // async global->LDS, 16 bytes per lane; LDS dest = wave-uniform base + lane*16
    __builtin_amdgcn_global_load_lds((gas_u32*)g, (las_u32*)l, 16, 0, 0);
}

__device__ inline float b2f(unsigned short u) {
    union { u32 i; float f; } c; c.i = ((u32)u) << 16; return c.f;
}
__device__ inline unsigned short f2b(float f) {   // round-to-nearest-even
    u32 x = __builtin_bit_cast(u32, f);
    return (unsigned short)((x + 0x7FFFu + ((x >> 16) & 1u)) >> 16);
}

// swizzled byte address into the 64x256-bf16 mid LDS tile (row stride 512B = 32 slots):
// slot ^= row&31 is bijective per row and de-conflicts stride-512B column reads.
__device__ inline int mid_addr(int row, int col) {
    return row * 512 + ((((col >> 3) ^ (row & 31)) << 4) | ((col & 7) << 1));
}

// ---------------- prep: zero deg + graph_starts (merged trivial kernels) ----------------
__global__ void prep_misc(int* __restrict__ deg, const int* __restrict__ batch,
                          int* __restrict__ gstart) {
    int bid = blockIdx.x;
    if (bid < 196) {
        int i = bid * 256 + threadIdx.x;
        if (i < N_NODES) deg[i] = 0;
    } else {
        int g = (bid - 196) * 256 + threadIdx.x;
        if (g > N_GRAPHS) return;
        if (g == N_GRAPHS) { gstart[g] = N_NODES; return; }
        int lo = 0, hi = N_NODES;
        while (lo < hi) { int mid = (lo + hi) >> 1; if (batch[mid] < g) lo = mid + 1; else hi = mid; }
        gstart[g] = lo;
    }
}

// ---------------- CSR build ----------------
__global__ void hist_dst(const int* __restrict__ dst, int* __restrict__ deg) {
    int e = blockIdx.x * blockDim.x + threadIdx.x;
    if (e < N_EDGES) atomicAdd(&deg[dst[e]], 1);
}
__global__ void scan_phase1(const int* __restrict__ deg, int* __restrict__ rowptr,
                            int* __restrict__ bsum, int n) {
    __shared__ int sh[SCAN_BS];
    int i = blockIdx.x * SCAN_BS + threadIdx.x;
    int v = (i < n) ? deg[i] : 0;
    sh[threadIdx.x] = v;
    __syncthreads();
    for (int off = 1; off < SCAN_BS; off <<= 1) {
        int t = (threadIdx.x >= off) ? sh[threadIdx.x - off] : 0;
        __syncthreads();
        sh[threadIdx.x] += t;
        __syncthreads();
    }
    if (i < n) rowptr[i] = sh[threadIdx.x] - v;
    if (threadIdx.x == SCAN_BS - 1) bsum[blockIdx.x] = sh[threadIdx.x];
}
__global__ void scan_phase2(int* __restrict__ bsum, int nb) {
    if (threadIdx.x == 0 && blockIdx.x == 0) {
        int run = 0;
        for (int b = 0; b < nb; b++) { int v = bsum[b]; bsum[b] = run; run += v; }
    }
}
__global__ void scan_phase3(int* __restrict__ rowptr, int* __restrict__ cursor,
                            const int* __restrict__ bsum, int n) {
    int i = blockIdx.x * SCAN_BS + threadIdx.x;
    if (i < n) {
        int v = rowptr[i] + bsum[blockIdx.x];
        rowptr[i] = v;
        cursor[i] = v;
    }
    if (i == 0) rowptr[n] = N_EDGES;
}
__global__ void fill_csr(const int* __restrict__ src, const int* __restrict__ dst,
                         int* __restrict__ cursor, int* __restrict__ col) {
    int e = blockIdx.x * blockDim.x + threadIdx.x;
    if (e < N_EDGES) {
        int p = atomicAdd(&cursor[dst[e]], 1);
        col[p] = src[e];
    }
}
// canonicalize neighbor order (atomic fill order is nondeterministic -> f32 sum order
// would vary call-to-call; harness requires identical output every call).
__global__ void sort_csr(const int* __restrict__ rowptr, int* __restrict__ col) {
    __shared__ int buf[4][SORT_CAP];
    int node = blockIdx.x * 4 + (threadIdx.x >> 6);
    if (node >= N_NODES) return;
    int lane = threadIdx.x & 63;
    int w = threadIdx.x >> 6;
    int s = rowptr[node], e = rowptr[node + 1];
    int L = e - s;
    if (L <= 1 || L > SORT_CAP) return;
    for (int i = lane; i < L; i += 64) buf[w][i] = col[s + i];
    asm volatile("s_waitcnt lgkmcnt(0) vmcnt(0)" ::: "memory");
    for (int pass = 0; pass < L; pass++) {
        int base = 2 * lane + (pass & 1);
        if (base + 1 < L) {
            int a = buf[w][base], b = buf[w][base + 1];
            if (a > b) { buf[w][base] = b; buf[w][base + 1] = a; }
        }
        asm volatile("s_waitcnt lgkmcnt(0)" ::: "memory");
    }
    for (int i = lane; i < L; i += 64) col[s + i] = buf[w][i];
}

// ---------------- conversions ----------------
__global__ void conv_x(const float4* __restrict__ in, ushort4* __restrict__ out, int n4) {
    int i = blockIdx.x * blockDim.x + threadIdx.x;
    if (i < n4) {
        float4 v = in[i];
        ushort4 o; o.x = f2b(v.x); o.y = f2b(v.y); o.z = f2b(v.z); o.w = f2b(v.w);
        out[i] = o;
    }
}
// merged: Wt[mat][n][k] = bf16(W[mat][k][n]) for mat<4; y==4 computes both layers' scale/shift
__global__ void conv_wss(const float* __restrict__ W0, const float* __restrict__ W1,
                         const float* __restrict__ W2, const float* __restrict__ W3,
                         unsigned short* __restrict__ Wt,
                         const float* __restrict__ b1a, const float* __restrict__ g1a,
                         const float* __restrict__ be1a, const float* __restrict__ m1a,
                         const float* __restrict__ v1a,
                         const float* __restrict__ b1b, const float* __restrict__ g1b,
                         const float* __restrict__ be1b, const float* __restrict__ m1b,
                         const float* __restrict__ v1b,
                         float* __restrict__ ss) {
    int mat = blockIdx.y;
    int n = blockIdx.x;
    int k = threadIdx.x;
    if (mat < 4) {
        const float* W = (mat == 0) ? W0 : (mat == 1) ? W1 : (mat == 2) ? W2 : W3;
        Wt[((size_t)mat << 16) + (size_t)n * 256 + k] = f2b(W[(size_t)k * 256 + n]);
    } else if (n == 0) {
        float s = g1a[k] * rsqrtf(v1a[k] + BN_EPS);
        ss[k] = s;
        ss[256 + k] = (b1a[k] - m1a[k]) * s + be1a[k];
    } else if (n == 1) {
        float s = g1b[k] * rsqrtf(v1b[k] + BN_EPS);
        ss[512 + k] = s;
        ss[768 + k] = (b1b[k] - m1b[k]) * s + be1b[k];
    }
}
// W1h[n][k] = bf16(lin1_W[k][n]); n in [0,768), k in [0,512)
__global__ void conv_w1h(const float* __restrict__ W, unsigned short* __restrict__ Wh) {
    int n = blockIdx.x;
    int k = threadIdx.x;          // 256 threads, 2 k each
    Wh[(size_t)n * 512 + k]       = f2b(W[(size_t)k * 768 + n]);
    Wh[(size_t)n * 512 + 256 + k] = f2b(W[(size_t)(256 + k) * 768 + n]);
}

// ---------------- gather aggregate (bf16): out[i] = feat[i] + sum_{j in N(i)} feat[j] ----------------
// one wave per node; two 32-lane halves own alternate edges; 16 B/lane loads; x4 unroll (8 streams/wave).
__global__ void gather_bf(const unsigned short* __restrict__ feat,
                          const int* __restrict__ col,
                          const int* __restrict__ rowptr,
                          unsigned short* __restrict__ out) {
    int node = blockIdx.x * 4 + (threadIdx.x >> 6);
    if (node >= N_NODES) return;
    int lane = threadIdx.x & 63;
    int half = lane >> 5;
    int d8 = (lane & 31) * 8;          // 8 bf16 = 16 B per lane
    float acc[8];
    #pragma unroll
    for (int j = 0; j < 8; j++) acc[j] = 0.f;
    if (half == 0) {
        us8 own = *reinterpret_cast<const us8*>(&feat[(size_t)node * DIM + d8]);
        #pragma unroll
        for (int j = 0; j < 8; j++) acc[j] = b2f((unsigned short)own[j]);
    }
    int s = rowptr[node], e = rowptr[node + 1];
    int i = s + half;
    for (; i + 6 < e; i += 8) {        // 4 edges per half per iter
        int n0 = col[i], n1 = col[i + 2], n2 = col[i + 4], n3 = col[i + 6];
        us8 v0 = *reinterpret_cast<const us8*>(&feat[(size_t)n0 * DIM + d8]);
        us8 v1 = *reinterpret_cast<const us8*>(&feat[(size_t)n1 * DIM + d8]);
        us8 v2 = *reinterpret_cast<const us8*>(&feat[(size_t)n2 * DIM + d8]);
        us8 v3 = *reinterpret_cast<const us8*>(&feat[(size_t)n3 * DIM + d8]);
        #pragma unroll
        for (int j = 0; j < 8; j++)
            acc[j] += (b2f((unsigned short)v0[j]) + b2f((unsigned short)v1[j]))
                    + (b2f((unsigned short)v2[j]) + b2f((unsigned short)v3[j]));
    }
    for (; i < e; i += 2) {
        int n0 = col[i];
        us8 v0 = *reinterpret_cast<const us8*>(&feat[(size_t)n0 * DIM + d8]);
        #pragma unroll
        for (int j = 0; j < 8; j++) acc[j] += b2f((unsigned short)v0[j]);
    }
    #pragma unroll
    for (int j = 0; j < 8; j++) acc[j] += __shfl_xor(acc[j], 32, 64);
    if (half == 0) {
        us8 o;
        #pragma unroll
        for (int j = 0; j < 8; j++) o[j] = (short)f2b(acc[j]);
        *reinterpret_cast<us8*>(&out[(size_t)node * DIM + d8]) = o;
    }
}

// ---------------- fused GIN MLP v3:  H = relu(relu(bn(A@W1)) @ W2 + b2) ------
// 256 threads, 64-row tile, 4 waves as 1M x 4N (wave 64x64), BK=64, K=256 -> 4 steps/phase.
// Single-buffered, full-drain __syncthreads; A/B LDS XOR-swizzled via pre-swizzled source.
__global__ __launch_bounds__(256, 2)
void fused_mlp(const unsigned short* __restrict__ A,
               const unsigned short* __restrict__ W1t,   // [256][256], W1t[n][k]
               const unsigned short* __restrict__ W2t,   // [256][256], W2t[n][k]
               const float* __restrict__ scale1,
               const float* __restrict__ shift1,
               const float* __restrict__ shift2,         // b2
               unsigned short* __restrict__ H, int M) {
    __shared__ __align__(16) unsigned short Asb[64 * 64];    // 8 KB  (64 rows x 64 k)
    __shared__ __align__(16) unsigned short Bsb[256 * 64];   // 32 KB (256 n x 64 k)
    __shared__ __align__(16) unsigned short midb[64 * 256];  // 32 KB, mid_addr swizzle

    int t = threadIdx.x;
    int wave = t >> 6, lane = t & 63;
    int m0 = blockIdx.x * 64;
    int wc = wave * 64;
    int rsel = lane & 15;
    int kgrp = lane >> 4;            // 16B chunk-in-subtile 0..3
    int cr = lane >> 4;

    float s1[4], sh1[4], sh2[4];
    #pragma unroll
    for (int n = 0; n < 4; n++) {
        int colg = wc + n * 16 + rsel;
        s1[n]  = scale1[colg];
        sh1[n] = shift1[colg];
        sh2[n] = shift2[colg];
    }

    f32x4 acc[4][4];
    #pragma unroll
    for (int m = 0; m < 4; m++)
        #pragma unroll
        for (int n = 0; n < 4; n++)
            acc[m][n] = (f32x4){0.f, 0.f, 0.f, 0.f};

    int arow0 = t >> 3, achk0 = t & 7;
    int arow1 = (256 + t) >> 3, achk1 = t & 7;
    const char* Abase = (const char*)A + (size_t)m0 * 512;

    // ---- phase 1: acc = A @ W1 ----
    for (int ks = 0; ks < 4; ks++) {
        size_t ko = (size_t)ks * 128;
        g2l16(Abase + (size_t)arow0 * 512 + ko + ((achk0 ^ (arow0 & 7)) << 4),
              (char*)Asb + (size_t)t * 16);
        g2l16(Abase + (size_t)arow1 * 512 + ko + ((achk1 ^ (arow1 & 7)) << 4),
              (char*)Asb + (size_t)(256 + t) * 16);
        #pragma unroll
        for (int i = 0; i < 8; i++) {
            int s = i * 256 + t;
            int brow = s >> 3, bchk = s & 7;
            g2l16((const char*)W1t + (size_t)brow * 512 + ko + ((bchk ^ (brow & 7)) << 4),
                  (char*)Bsb + (size_t)s * 16);
        }
        __syncthreads();

        #pragma unroll
        for (int ksub = 0; ksub < 2; ksub++) {
            bf16x8 af[4], bfr[4];
            int kchunk = ksub * 4 + kgrp;
            #pragma unroll
            for (int m = 0; m < 4; m++) {
                int row = m * 16 + rsel;
                af[m] = *(const bf16x8*)((const char*)Asb + (size_t)row * 128
                                         + ((kchunk ^ (row & 7)) << 4));
            }
            #pragma unroll
            for (int n = 0; n < 4; n++) {
                int row = wc + n * 16 + rsel;
                bfr[n] = *(const bf16x8*)((const char*)Bsb + (size_t)row * 128
                                          + ((kchunk ^ (row & 7)) << 4));
            }
            #pragma unroll
            for (int m = 0; m < 4; m++)
                #pragma unroll
                for (int n = 0; n < 4; n++)
                    acc[m][n] = __builtin_amdgcn_mfma_f32_16x16x32_bf16(af[m], bfr[n], acc[m][n], 0, 0, 0);
        }
        __syncthreads();
    }

    // ---- epilogue 1: mid = relu(acc*scale1 + shift1) -> bf16 -> swizzled LDS; reset acc ----
    #pragma unroll
    for (int n = 0; n < 4; n++) {
        int colg = wc + n * 16 + rsel;
        #pragma unroll
        for (int m = 0; m < 4; m++) {
            int rowb = m * 16 + cr * 4;
            #pragma unroll
            for (int r = 0; r < 4; r++) {
                float v = fmaxf(acc[m][n][r] * s1[n] + sh1[n], 0.f);
                *(unsigned short*)((char*)midb + mid_addr(rowb + r, colg)) = f2b(v);
                acc[m][n][r] = 0.f;
            }
        }
    }

    // ---- phase 2: acc = mid @ W2 ----
    for (int ks = 0; ks < 4; ks++) {
        size_t ko = (size_t)ks * 128;
        #pragma unroll
        for (int i = 0; i < 8; i++) {
            int s = i * 256 + t;
            int brow = s >> 3, bchk = s & 7;
            g2l16((const char*)W2t + (size_t)brow * 512 + ko + ((bchk ^ (brow & 7)) << 4),
                  (char*)Bsb + (size_t)s * 16);
        }
        __syncthreads();

        #pragma unroll
        for (int ksub = 0; ksub < 2; ksub++) {
            bf16x8 af[4], bfr[4];
            int kchunk = ksub * 4 + kgrp;
            int kcol = ks * 64 + ksub * 32 + kgrp * 8;
            #pragma unroll
            for (int m = 0; m < 4; m++)
                af[m] = *(const bf16x8*)((const char*)midb + mid_addr(m * 16 + rsel, kcol));
            #pragma unroll
            for (int n = 0; n < 4; n++) {
                int row = wc + n * 16 + rsel;
                bfr[n] = *(const bf16x8*)((const char*)Bsb + (size_t)row * 128
                                          + ((kchunk ^ (row & 7)) << 4));
            }
            #pragma unroll
            for (int m = 0; m < 4; m++)
                #pragma unroll
                for (int n = 0; n < 4; n++)
                    acc[m][n] = __builtin_amdgcn_mfma_f32_16x16x32_bf16(af[m], bfr[n], acc[m][n], 0, 0, 0);
        }
        __syncthreads();
    }

    // ---- epilogue 2: H = relu(acc + b2) ----
    #pragma unroll
    for (int n = 0; n < 4; n++) {
        int colg = wc + n * 16 + rsel;
        #pragma unroll
        for (int m = 0; m < 4; m++) {
            int rowb = m0 + m * 16 + cr * 4;
            #pragma unroll
            for (int r = 0; r < 4; r++) {
                int row = rowb + r;
                if (row < M) {
                    float v = fmaxf(acc[m][n][r] + sh2[n], 0.f);
                    H[(size_t)row * 256 + colg] = f2b(v);
                }
            }
        }
    }
}

// ---------------- pooling v3: vectorized us8 loads, bf16 pcat output ----------------
__global__ void pool_seg(const unsigned short* __restrict__ h1,
                         const unsigned short* __restrict__ h2,
                         const int* __restrict__ gstart,
                         unsigned short* __restrict__ pcat) {    // [GPAD][512] bf16
    __shared__ float red1[8][256];
    __shared__ float red2[8][256];
    int g = blockIdx.x;
    int t = threadIdx.x;
    int sub = t >> 5;
    int d8 = (t & 31) * 8;
    float a1[8], a2[8];
    #pragma unroll
    for (int j = 0; j < 8; j++) { a1[j] = 0.f; a2[j] = 0.f; }
    int s = gstart[g], e = gstart[g + 1];
    for (int n = s + sub; n < e; n += 8) {
        us8 v1 = *reinterpret_cast<const us8*>(&h1[(size_t)n * DIM + d8]);
        us8 v2 = *reinterpret_cast<const us8*>(&h2[(size_t)n * DIM + d8]);
        #pragma unroll
        for (int j = 0; j < 8; j++) {
            a1[j] += b2f((unsigned short)v1[j]);
            a2[j] += b2f((unsigned short)v2[j]);
        }
    }
    #pragma unroll
    for (int j = 0; j < 8; j++) {
        red1[sub][d8 + j] = a1[j];
        red2[sub][d8 + j] = a2[j];
    }
    __syncthreads();
    float o1 = 0.f, o2 = 0.f;
    #pragma unroll
    for (int k = 0; k < 8; k++) { o1 += red1[k][t]; o2 += red2[k][t]; }
    pcat[(size_t)g * 512 + t]       = f2b(o1);
    pcat[(size_t)g * 512 + 256 + t] = f2b(o2);
}

// ---------------- head stage 1 (MFMA): Hf[500 x 768] = relu(pcat @ lin1_W + b1) ----------------
__global__ __launch_bounds__(256)
void head1_mfma(const unsigned short* __restrict__ A,    // [GPAD][512] bf16 (pcat)
                const unsigned short* __restrict__ Wh,   // [768][512] bf16, Wh[n][k]
                const float* __restrict__ b1,
                float* __restrict__ Hf) {                // [GPAD][768] f32
    __shared__ __align__(16) unsigned short Asb[64 * 64];    // 8 KB
    __shared__ __align__(16) unsigned short Bsb[256 * 64];   // 32 KB

    int t = threadIdx.x;
    int wave = t >> 6, lane = t & 63;
    int n0 = blockIdx.x * 256;
    int m0 = blockIdx.y * 64;
    int wc = wave * 64;
    int rsel = lane & 15;
    int kgrp = lane >> 4;
    int cr = lane >> 4;

    float bb[4];
    #pragma unroll
    for (int n = 0; n < 4; n++) bb[n] = b1[n0 + wc + n * 16 + rsel];

    f32x4 acc[4][4];
    #pragma unroll
    for (int m = 0; m < 4; m++)
        #pragma unroll
        for (int n = 0; n < 4; n++)
            acc[m][n] = (f32x4){0.f, 0.f, 0.f, 0.f};

    int arow0 = t >> 3, achk0 = t & 7;
    int arow1 = (256 + t) >> 3, achk1 = t & 7;
    const char* Abase = (const char*)A + (size_t)m0 * 1024;   // row stride 512 bf16 = 1024 B

    for (int ks = 0; ks < 8; ks++) {
        size_t ko = (size_t)ks * 128;   // 64 bf16 per step
        g2l16(Abase + (size_t)arow0 * 1024 + ko + ((achk0 ^ (arow0 & 7)) << 4),
              (char*)Asb + (size_t)t * 16);
        g2l16(Abase + (size_t)arow1 * 1024 + ko + ((achk1 ^ (arow1 & 7)) << 4),
              (char*)Asb + (size_t)(256 + t) * 16);
        #pragma unroll
        for (int i = 0; i < 8; i++) {
            int s = i * 256 + t;
            int brow = s >> 3, bchk = s & 7;
            g2l16((const char*)Wh + (size_t)(n0 + brow) * 1024 + ko + ((bchk ^ (brow & 7)) << 4),
                  (char*)Bsb + (size_t)s * 16);
        }
        __syncthreads();

        #pragma unroll
        for (int ksub = 0; ksub < 2; ksub++) {
            bf16x8 af[4], bfr[4];
            int kchunk = ksub * 4 + kgrp;
            #pragma unroll
            for (int m = 0; m < 4; m++) {
                int row = m * 16 + rsel;
                af[m] = *(const bf16x8*)((const char*)Asb + (size_t)row * 128
                                         + ((kchunk ^ (row & 7)) << 4));
            }
            #pragma unroll
            for (int n = 0; n < 4; n++) {
                int row = wc + n * 16 + rsel;
                bfr[n] = *(const bf16x8*)((const char*)Bsb + (size_t)row * 128
                                          + ((kchunk ^ (row & 7)) << 4));
            }
            #pragma unroll
            for (int m = 0; m < 4; m++)
                #pragma unroll
                for (int n = 0; n < 4; n++)
                    acc[m][n] = __builtin_amdgcn_mfma_f32_16x16x32_bf16(af[m], bfr[n], acc[m][n], 0, 0, 0);
        }
        __syncthreads();
    }

    // epilogue: Hf = relu(acc + b1), f32 store; C/D map col=lane&15, row=(lane>>4)*4+reg
    #pragma unroll
    for (int n = 0; n < 4; n++) {
        int colg = n0 + wc + n * 16 + rsel;
        #pragma unroll
        for (int m = 0; m < 4; m++) {
            int rowb = m0 + m * 16 + cr * 4;
            #pragma unroll
            for (int r = 0; r < 4; r++) {
                int row = rowb + r;
                if (row < N_GRAPHS)
                    Hf[(size_t)row * 768 + colg] = fmaxf(acc[m][n][r] + bb[n], 0.f);
            }
        }
    }
}

// ---------------- head stage 2: GEMV + log_softmax ----------------
__global__ void head2(const float* __restrict__ Hf, const float* __restrict__ W2,
                      const float* __restrict__ b2, float* __restrict__ out) {
    int g = blockIdx.x;
    int lane = threadIdx.x;   // 64
    float part[N_OUT];
    #pragma unroll
    for (int o = 0; o < N_OUT; o++) part[o] = 0.f;
    for (int k = lane; k < 768; k += 64) {
        float hv = Hf[(size_t)g * 768 + k];
        #pragma unroll
        for (int o = 0; o < N_OUT; o++) part[o] += hv * W2[(size_t)k * N_OUT + o];
    }
    #pragma unroll
    for (int o = 0; o < N_OUT; o++) {
        #pragma unroll
        for (int off = 32; off > 0; off >>= 1)
            part[o] += __shfl_down(part[o], off, 64);
    }
    if (lane == 0) {
        float logits[N_OUT];
        float mx = -1e30f;
        #pragma unroll
        for (int o = 0; o < N_OUT; o++) { logits[o] = part[o] + b2[o]; mx = fmaxf(mx, logits[o]); }
        float ssum = 0.f;
        #pragma unroll
        for (int o = 0; o < N_OUT; o++) ssum += expf(logits[o] - mx);
        float lse = logf(ssum);
        #pragma unroll
        for (int o = 0; o < N_OUT; o++)
            out[(size_t)g * N_OUT + o] = logits[o] - mx - lse;
    }
}

extern "C" void kernel_launch(void* const* d_in, const int* in_sizes, int n_in,
                              void* d_out, int out_size, void* d_ws, size_t ws_size,
                              hipStream_t stream) {
    const float* x     = (const float*)d_in[0];
    const int*   ei    = (const int*)d_in[1];
    const int*   batch = (const int*)d_in[2];
    const float* W1a = (const float*)d_in[3];
    const float* b1a = (const float*)d_in[4];
    const float* g1a = (const float*)d_in[5];
    const float* be1a= (const float*)d_in[6];
    const float* m1a = (const float*)d_in[7];
    const float* v1a = (const float*)d_in[8];
    const float* W2a = (const float*)d_in[9];
    const float* b2a = (const float*)d_in[10];
    const float* W1b = (const float*)d_in[11];
    const float* b1b = (const float*)d_in[12];
    const float* g1b = (const float*)d_in[13];
    const float* be1b= (const float*)d_in[14];
    const float* m1b = (const float*)d_in[15];
    const float* v1b = (const float*)d_in[16];
    const float* W2b = (const float*)d_in[17];
    const float* b2b = (const float*)d_in[18];
    const float* lin1_W = (const float*)d_in[19];
    const float* lin1_b = (const float*)d_in[20];
    const float* lin2_W = (const float*)d_in[21];
    const float* lin2_b = (const float*)d_in[22];

    const size_t NBUF = (size_t)MPAD * DIM;
    char* ws = (char*)d_ws;
    unsigned short* agg  = (unsigned short*)ws;            ws += NBUF * 2;
    unsigned short* h1   = (unsigned short*)ws;            ws += NBUF * 2;
    unsigned short* h2   = (unsigned short*)ws;            ws += NBUF * 2;
    unsigned short* x_bf = (unsigned short*)ws;            ws += (size_t)N_NODES * DIM * 2;
    unsigned short* Wt   = (unsigned short*)ws;            ws += 4 * 65536 * 2;
    unsigned short* W1h  = (unsigned short*)ws;            ws += (size_t)768 * 512 * 2;
    float* ss    = (float*)ws;                             ws += 4 * 256 * 4;   // scaleA,shiftA,scaleB,shiftB
    unsigned short* pcat = (unsigned short*)ws;            ws += (size_t)GPAD * 512 * 2;
    float* Hf    = (float*)ws;                             ws += (size_t)GPAD * 768 * 4;
    int* deg     = (int*)ws;                               ws += (size_t)N_NODES * 4;
    int* cursor  = (int*)ws;                               ws += (size_t)N_NODES * 4;
    int* rowptr  = (int*)ws;                               ws += (size_t)(N_NODES + 1) * 4;
    int* bsum    = (int*)ws;                               ws += 64 * 4;
    int* col     = (int*)ws;                               ws += (size_t)N_EDGES * 4;
    int* gstart  = (int*)ws;

    const int* srcE = ei;
    const int* dstE = ei + N_EDGES;

    const int nscan = (N_NODES + SCAN_BS - 1) / SCAN_BS;

    // ---- CSR build (by dst), shared by both layers; sorted for determinism ----
    prep_misc<<<198, 256, 0, stream>>>(deg, batch, gstart);
    hist_dst<<<(N_EDGES + 255) / 256, 256, 0, stream>>>(dstE, deg);
    scan_phase1<<<nscan, SCAN_BS, 0, stream>>>(deg, rowptr, bsum, N_NODES);
    scan_phase2<<<1, 64, 0, stream>>>(bsum, nscan);
    scan_phase3<<<nscan, SCAN_BS, 0, stream>>>(rowptr, cursor, bsum, N_NODES);
    fill_csr<<<(N_EDGES + 255) / 256, 256, 0, stream>>>(srcE, dstE, cursor, col);
    sort_csr<<<(N_NODES + 3) / 4, 256, 0, stream>>>(rowptr, col);

    // ---- precompute ----
    conv_x<<<(N_NODES * DIM / 4 + 255) / 256, 256, 0, stream>>>(
        (const float4*)x, (ushort4*)x_bf, N_NODES * DIM / 4);
    dim3 wss_grid(256, 5);
    conv_wss<<<wss_grid, 256, 0, stream>>>(W1a, W2a, W1b, W2b, Wt,
                                           b1a, g1a, be1a, m1a, v1a,
                                           b1b, g1b, be1b, m1b, v1b, ss);
    conv_w1h<<<768, 256, 0, stream>>>(lin1_W, W1h);

    // ---- layer 1 ----
    gather_bf<<<(N_NODES + 3) / 4, 256, 0, stream>>>(x_bf, col, rowptr, agg);
    fused_mlp<<<MPAD / 64, 256, 0, stream>>>(agg, Wt + 0 * 65536, Wt + 1 * 65536,
                                             ss, ss + 256, b2a, h1, N_NODES);

    // ---- layer 2 ----
    gather_bf<<<(N_NODES + 3) / 4, 256, 0, stream>>>(h1, col, rowptr, agg);
    fused_mlp<<<MPAD / 64, 256, 0, stream>>>(agg, Wt + 2 * 65536, Wt + 3 * 65536,
                                             ss + 512, ss + 768, b2b, h2, N_NODES);

    // ---- pooling + head ----
    pool_seg<<<N_GRAPHS, 256, 0, stream>>>(h1, h2, gstart, pcat);
    dim3 h1grid(3, 8);
    head1_mfma<<<h1grid, 256, 0, stream>>>(pcat, W1h, lin1_b, Hf);
    head2<<<N_GRAPHS, 64, 0, stream>>>(Hf, lin2_W, lin2_b, (float*)d_out);
}

// Round 19
// 339.823 us; speedup vs baseline: 1.6726x; 1.0063x over previous
//
#include <hip/hip_runtime.h>

#define N_NODES 50000
#define MPAD 50176            // 784*64, node-buffer row padding for GEMM staging
#define N_EDGES 800000
#define DIM 256
#define N_GRAPHS 500
#define GPAD 512              // padded graph rows for head1 MFMA staging
#define N_OUT 10
#define BN_EPS 1e-5f
#define SCAN_BS 1024
#define SORT_CAP 96           // max degree handled by sort (Poisson(16): P(deg>96) ~ 0)

typedef unsigned int u32;
typedef short bf16x8 __attribute__((ext_vector_type(8)));
typedef unsigned short us8 __attribute__((ext_vector_type(8)));
typedef float f32x4 __attribute__((ext_vector_type(4)));

typedef __attribute__((address_space(1))) const unsigned int gas_u32;
typedef __attribute__((address_space(3))) unsigned int las_u32;

__device__ inline void g2l16(const void* g, void* l) {
    // async global->LDS, 16 bytes per lane; LDS dest = wave-uniform base + lane*16
    __builtin_amdgcn_global_load_lds((gas_u32*)g, (las_u32*)l, 16, 0, 0);
}

__device__ inline float b2f(unsigned short u) {
    union { u32 i; float f; } c; c.i = ((u32)u) << 16; return c.f;
}
__device__ inline unsigned short f2b(float f) {   // round-to-nearest-even
    u32 x = __builtin_bit_cast(u32, f);
    return (unsigned short)((x + 0x7FFFu + ((x >> 16) & 1u)) >> 16);
}

// swizzled byte address into the 64x256-bf16 mid LDS tile (row stride 512B = 32 slots):
// slot ^= row&31 is bijective per row and de-conflicts stride-512B column reads.
__device__ inline int mid_addr(int row, int col) {
    return row * 512 + ((((col >> 3) ^ (row & 31)) << 4) | ((col & 7) << 1));
}

// ---------------- prep: zero deg + graph_starts (merged trivial kernels) ----------------
__global__ void prep_misc(int* __restrict__ deg, const int* __restrict__ batch,
                          int* __restrict__ gstart) {
    int bid = blockIdx.x;
    if (bid < 196) {
        int i = bid * 256 + threadIdx.x;
        if (i < N_NODES) deg[i] = 0;
    } else {
        int g = (bid - 196) * 256 + threadIdx.x;
        if (g > N_GRAPHS) return;
        if (g == N_GRAPHS) { gstart[g] = N_NODES; return; }
        int lo = 0, hi = N_NODES;
        while (lo < hi) { int mid = (lo + hi) >> 1; if (batch[mid] < g) lo = mid + 1; else hi = mid; }
        gstart[g] = lo;
    }
}

// ---------------- CSR build ----------------
__global__ void hist_dst(const int* __restrict__ dst, int* __restrict__ deg) {
    int e = blockIdx.x * blockDim.x + threadIdx.x;
    if (e < N_EDGES) atomicAdd(&deg[dst[e]], 1);
}
__global__ void scan_phase1(const int* __restrict__ deg, int* __restrict__ rowptr,
                            int* __restrict__ bsum, int n) {
    __shared__ int sh[SCAN_BS];
    int i = blockIdx.x * SCAN_BS + threadIdx.x;
    int v = (i < n) ? deg[i] : 0;
    sh[threadIdx.x] = v;
    __syncthreads();
    for (int off = 1; off < SCAN_BS; off <<= 1) {
        int t = (threadIdx.x >= off) ? sh[threadIdx.x - off] : 0;
        __syncthreads();
        sh[threadIdx.x] += t;
        __syncthreads();
    }
    if (i < n) rowptr[i] = sh[threadIdx.x] - v;
    if (threadIdx.x == SCAN_BS - 1) bsum[blockIdx.x] = sh[threadIdx.x];
}
__global__ void scan_phase2(int* __restrict__ bsum, int nb) {
    if (threadIdx.x == 0 && blockIdx.x == 0) {
        int run = 0;
        for (int b = 0; b < nb; b++) { int v = bsum[b]; bsum[b] = run; run += v; }
    }
}
__global__ void scan_phase3(int* __restrict__ rowptr, int* __restrict__ cursor,
                            const int* __restrict__ bsum, int n) {
    int i = blockIdx.x * SCAN_BS + threadIdx.x;
    if (i < n) {
        int v = rowptr[i] + bsum[blockIdx.x];
        rowptr[i] = v;
        cursor[i] = v;
    }
    if (i == 0) rowptr[n] = N_EDGES;
}
// col stored as ushort (node ids < 65536). Concurrent stores to distinct bytes are
// race-free per the HIP/C++ memory model; determinism of VALUES is irrelevant to
// fill order because sort_csr canonicalizes each segment afterwards.
__global__ void fill_csr(const int* __restrict__ src, const int* __restrict__ dst,
                         int* __restrict__ cursor, unsigned short* __restrict__ col) {
    int e = blockIdx.x * blockDim.x + threadIdx.x;
    if (e < N_EDGES) {
        int p = atomicAdd(&cursor[dst[e]], 1);
        col[p] = (unsigned short)src[e];
    }
}
// canonicalize neighbor order (atomic fill order is nondeterministic -> f32 sum order
// would vary call-to-call; harness requires identical output every call).
__global__ void sort_csr(const int* __restrict__ rowptr, unsigned short* __restrict__ col) {
    __shared__ unsigned short buf[4][SORT_CAP];
    int node = blockIdx.x * 4 + (threadIdx.x >> 6);
    if (node >= N_NODES) return;
    int lane = threadIdx.x & 63;
    int w = threadIdx.x >> 6;
    int s = rowptr[node], e = rowptr[node + 1];
    int L = e - s;
    if (L <= 1 || L > SORT_CAP) return;
    for (int i = lane; i < L; i += 64) buf[w][i] = col[s + i];
    asm volatile("s_waitcnt lgkmcnt(0) vmcnt(0)" ::: "memory");
    for (int pass = 0; pass < L; pass++) {
        int base = 2 * lane + (pass & 1);
        if (base + 1 < L) {
            unsigned short a = buf[w][base], b = buf[w][base + 1];
            if (a > b) { buf[w][base] = b; buf[w][base + 1] = a; }
        }
        asm volatile("s_waitcnt lgkmcnt(0)" ::: "memory");
    }
    for (int i = lane; i < L; i += 64) col[s + i] = buf[w][i];
}

// ---------------- conversions ----------------
__global__ void conv_x(const float4* __restrict__ in, ushort4* __restrict__ out, int n4) {
    int i = blockIdx.x * blockDim.x + threadIdx.x;
    if (i < n4) {
        float4 v = in[i];
        ushort4 o; o.x = f2b(v.x); o.y = f2b(v.y); o.z = f2b(v.z); o.w = f2b(v.w);
        out[i] = o;
    }
}
// merged: Wt[mat][n][k] = bf16(W[mat][k][n]) for mat<4; y==4 computes both layers' scale/shift
__global__ void conv_wss(const float* __restrict__ W0, const float* __restrict__ W1,
                         const float* __restrict__ W2, const float* __restrict__ W3,
                         unsigned short* __restrict__ Wt,
                         const float* __restrict__ b1a, const float* __restrict__ g1a,
                         const float* __restrict__ be1a, const float* __restrict__ m1a,
                         const float* __restrict__ v1a,
                         const float* __restrict__ b1b, const float* __restrict__ g1b,
                         const float* __restrict__ be1b, const float* __restrict__ m1b,
                         const float* __restrict__ v1b,
                         float* __restrict__ ss) {
    int mat = blockIdx.y;
    int n = blockIdx.x;
    int k = threadIdx.x;
    if (mat < 4) {
        const float* W = (mat == 0) ? W0 : (mat == 1) ? W1 : (mat == 2) ? W2 : W3;
        Wt[((size_t)mat << 16) + (size_t)n * 256 + k] = f2b(W[(size_t)k * 256 + n]);
    } else if (n == 0) {
        float s = g1a[k] * rsqrtf(v1a[k] + BN_EPS);
        ss[k] = s;
        ss[256 + k] = (b1a[k] - m1a[k]) * s + be1a[k];
    } else if (n == 1) {
        float s = g1b[k] * rsqrtf(v1b[k] + BN_EPS);
        ss[512 + k] = s;
        ss[768 + k] = (b1b[k] - m1b[k]) * s + be1b[k];
    }
}
// W1h[n][k] = bf16(lin1_W[k][n]); n in [0,768), k in [0,512)
__global__ void conv_w1h(const float* __restrict__ W, unsigned short* __restrict__ Wh) {
    int n = blockIdx.x;
    int k = threadIdx.x;          // 256 threads, 2 k each
    Wh[(size_t)n * 512 + k]       = f2b(W[(size_t)k * 768 + n]);
    Wh[(size_t)n * 512 + 256 + k] = f2b(W[(size_t)(256 + k) * 768 + n]);
}

// ---------------- gather aggregate (bf16): out[i] = feat[i] + sum_{j in N(i)} feat[j] ----------------
// one wave per node; two 32-lane halves own alternate edges; 16 B/lane loads; x4 unroll (8 streams/wave).
__global__ void gather_bf(const unsigned short* __restrict__ feat,
                          const unsigned short* __restrict__ col,
                          const int* __restrict__ rowptr,
                          unsigned short* __restrict__ out) {
    int node = blockIdx.x * 4 + (threadIdx.x >> 6);
    if (node >= N_NODES) return;
    int lane = threadIdx.x & 63;
    int half = lane >> 5;
    int d8 = (lane & 31) * 8;          // 8 bf16 = 16 B per lane
    float acc[8];
    #pragma unroll
    for (int j = 0; j < 8; j++) acc[j] = 0.f;
    if (half == 0) {
        us8 own = *reinterpret_cast<const us8*>(&feat[(size_t)node * DIM + d8]);
        #pragma unroll
        for (int j = 0; j < 8; j++) acc[j] = b2f((unsigned short)own[j]);
    }
    int s = rowptr[node], e = rowptr[node + 1];
    int i = s + half;
    for (; i + 6 < e; i += 8) {        // 4 edges per half per iter
        int n0 = col[i], n1 = col[i + 2], n2 = col[i + 4], n3 = col[i + 6];
        us8 v0 = *reinterpret_cast<const us8*>(&feat[(size_t)n0 * DIM + d8]);
        us8 v1 = *reinterpret_cast<const us8*>(&feat[(size_t)n1 * DIM + d8]);
        us8 v2 = *reinterpret_cast<const us8*>(&feat[(size_t)n2 * DIM + d8]);
        us8 v3 = *reinterpret_cast<const us8*>(&feat[(size_t)n3 * DIM + d8]);
        #pragma unroll
        for (int j = 0; j < 8; j++)
            acc[j] += (b2f((unsigned short)v0[j]) + b2f((unsigned short)v1[j]))
                    + (b2f((unsigned short)v2[j]) + b2f((unsigned short)v3[j]));
    }
    for (; i < e; i += 2) {
        int n0 = col[i];
        us8 v0 = *reinterpret_cast<const us8*>(&feat[(size_t)n0 * DIM + d8]);
        #pragma unroll
        for (int j = 0; j < 8; j++) acc[j] += b2f((unsigned short)v0[j]);
    }
    #pragma unroll
    for (int j = 0; j < 8; j++) acc[j] += __shfl_xor(acc[j], 32, 64);
    if (half == 0) {
        us8 o;
        #pragma unroll
        for (int j = 0; j < 8; j++) o[j] = (short)f2b(acc[j]);
        *reinterpret_cast<us8*>(&out[(size_t)node * DIM + d8]) = o;
    }
}

// ---------------- fused GIN MLP v3:  H = relu(relu(bn(A@W1)) @ W2 + b2) ------
// 256 threads, 64-row tile, 4 waves as 1M x 4N (wave 64x64), BK=64, K=256 -> 4 steps/phase.
// Single-buffered, full-drain __syncthreads; A/B LDS XOR-swizzled via pre-swizzled source.
__global__ __launch_bounds__(256, 2)
void fused_mlp(const unsigned short* __restrict__ A,
               const unsigned short* __restrict__ W1t,   // [256][256], W1t[n][k]
               const unsigned short* __restrict__ W2t,   // [256][256], W2t[n][k]
               const float* __restrict__ scale1,
               const float* __restrict__ shift1,
               const float* __restrict__ shift2,         // b2
               unsigned short* __restrict__ H, int M) {
    __shared__ __align__(16) unsigned short Asb[64 * 64];    // 8 KB  (64 rows x 64 k)
    __shared__ __align__(16) unsigned short Bsb[256 * 64];   // 32 KB (256 n x 64 k)
    __shared__ __align__(16) unsigned short midb[64 * 256];  // 32 KB, mid_addr swizzle

    int t = threadIdx.x;
    int wave = t >> 6, lane = t & 63;
    int m0 = blockIdx.x * 64;
    int wc = wave * 64;
    int rsel = lane & 15;
    int kgrp = lane >> 4;            // 16B chunk-in-subtile 0..3
    int cr = lane >> 4;

    float s1[4], sh1[4], sh2[4];
    #pragma unroll
    for (int n = 0; n < 4; n++) {
        int colg = wc + n * 16 + rsel;
        s1[n]  = scale1[colg];
        sh1[n] = shift1[colg];
        sh2[n] = shift2[colg];
    }

    f32x4 acc[4][4];
    #pragma unroll
    for (int m = 0; m < 4; m++)
        #pragma unroll
        for (int n = 0; n < 4; n++)
            acc[m][n] = (f32x4){0.f, 0.f, 0.f, 0.f};

    int arow0 = t >> 3, achk0 = t & 7;
    int arow1 = (256 + t) >> 3, achk1 = t & 7;
    const char* Abase = (const char*)A + (size_t)m0 * 512;

    // ---- phase 1: acc = A @ W1 ----
    for (int ks = 0; ks < 4; ks++) {
        size_t ko = (size_t)ks * 128;
        g2l16(Abase + (size_t)arow0 * 512 + ko + ((achk0 ^ (arow0 & 7)) << 4),
              (char*)Asb + (size_t)t * 16);
        g2l16(Abase + (size_t)arow1 * 512 + ko + ((achk1 ^ (arow1 & 7)) << 4),
              (char*)Asb + (size_t)(256 + t) * 16);
        #pragma unroll
        for (int i = 0; i < 8; i++) {
            int s = i * 256 + t;
            int brow = s >> 3, bchk = s & 7;
            g2l16((const char*)W1t + (size_t)brow * 512 + ko + ((bchk ^ (brow & 7)) << 4),
                  (char*)Bsb + (size_t)s * 16);
        }
        __syncthreads();

        #pragma unroll
        for (int ksub = 0; ksub < 2; ksub++) {
            bf16x8 af[4], bfr[4];
            int kchunk = ksub * 4 + kgrp;
            #pragma unroll
            for (int m = 0; m < 4; m++) {
                int row = m * 16 + rsel;
                af[m] = *(const bf16x8*)((const char*)Asb + (size_t)row * 128
                                         + ((kchunk ^ (row & 7)) << 4));
            }
            #pragma unroll
            for (int n = 0; n < 4; n++) {
                int row = wc + n * 16 + rsel;
                bfr[n] = *(const bf16x8*)((const char*)Bsb + (size_t)row * 128
                                          + ((kchunk ^ (row & 7)) << 4));
            }
            #pragma unroll
            for (int m = 0; m < 4; m++)
                #pragma unroll
                for (int n = 0; n < 4; n++)
                    acc[m][n] = __builtin_amdgcn_mfma_f32_16x16x32_bf16(af[m], bfr[n], acc[m][n], 0, 0, 0);
        }
        __syncthreads();
    }

    // ---- epilogue 1: mid = relu(acc*scale1 + shift1) -> bf16 -> swizzled LDS; reset acc ----
    #pragma unroll
    for (int n = 0; n < 4; n++) {
        int colg = wc + n * 16 + rsel;
        #pragma unroll
        for (int m = 0; m < 4; m++) {
            int rowb = m * 16 + cr * 4;
            #pragma unroll
            for (int r = 0; r < 4; r++) {
                float v = fmaxf(acc[m][n][r] * s1[n] + sh1[n], 0.f);
                *(unsigned short*)((char*)midb + mid_addr(rowb + r, colg)) = f2b(v);
                acc[m][n][r] = 0.f;
            }
        }
    }

    // ---- phase 2: acc = mid @ W2 ----
    for (int ks = 0; ks < 4; ks++) {
        size_t ko = (size_t)ks * 128;
        #pragma unroll
        for (int i = 0; i < 8; i++) {
            int s = i * 256 + t;
            int brow = s >> 3, bchk = s & 7;
            g2l16((const char*)W2t + (size_t)brow * 512 + ko + ((bchk ^ (brow & 7)) << 4),
                  (char*)Bsb + (size_t)s * 16);
        }
        __syncthreads();

        #pragma unroll
        for (int ksub = 0; ksub < 2; ksub++) {
            bf16x8 af[4], bfr[4];
            int kchunk = ksub * 4 + kgrp;
            int kcol = ks * 64 + ksub * 32 + kgrp * 8;
            #pragma unroll
            for (int m = 0; m < 4; m++)
                af[m] = *(const bf16x8*)((const char*)midb + mid_addr(m * 16 + rsel, kcol));
            #pragma unroll
            for (int n = 0; n < 4; n++) {
                int row = wc + n * 16 + rsel;
                bfr[n] = *(const bf16x8*)((const char*)Bsb + (size_t)row * 128
                                          + ((kchunk ^ (row & 7)) << 4));
            }
            #pragma unroll
            for (int m = 0; m < 4; m++)
                #pragma unroll
                for (int n = 0; n < 4; n++)
                    acc[m][n] = __builtin_amdgcn_mfma_f32_16x16x32_bf16(af[m], bfr[n], acc[m][n], 0, 0, 0);
        }
        __syncthreads();
    }

    // ---- epilogue 2: H = relu(acc + b2) ----
    #pragma unroll
    for (int n = 0; n < 4; n++) {
        int colg = wc + n * 16 + rsel;
        #pragma unroll
        for (int m = 0; m < 4; m++) {
            int rowb = m0 + m * 16 + cr * 4;
            #pragma unroll
            for (int r = 0; r < 4; r++) {
                int row = rowb + r;
                if (row < M) {
                    float v = fmaxf(acc[m][n][r] + sh2[n], 0.f);
                    H[(size_t)row * 256 + colg] = f2b(v);
                }
            }
        }
    }
}

// ---------------- pooling v3: vectorized us8 loads, bf16 pcat output ----------------
__global__ void pool_seg(const unsigned short* __restrict__ h1,
                         const unsigned short* __restrict__ h2,
                         const int* __restrict__ gstart,
                         unsigned short* __restrict__ pcat) {    // [GPAD][512] bf16
    __shared__ float red1[8][256];
    __shared__ float red2[8][256];
    int g = blockIdx.x;
    int t = threadIdx.x;
    int sub = t >> 5;
    int d8 = (t & 31) * 8;
    float a1[8], a2[8];
    #pragma unroll
    for (int j = 0; j < 8; j++) { a1[j] = 0.f; a2[j] = 0.f; }
    int s = gstart[g], e = gstart[g + 1];
    for (int n = s + sub; n < e; n += 8) {
        us8 v1 = *reinterpret_cast<const us8*>(&h1[(size_t)n * DIM + d8]);
        us8 v2 = *reinterpret_cast<const us8*>(&h2[(size_t)n * DIM + d8]);
        #pragma unroll
        for (int j = 0; j < 8; j++) {
            a1[j] += b2f((unsigned short)v1[j]);
            a2[j] += b2f((unsigned short)v2[j]);
        }
    }
    #pragma unroll
    for (int j = 0; j < 8; j++) {
        red1[sub][d8 + j] = a1[j];
        red2[sub][d8 + j] = a2[j];
    }
    __syncthreads();
    float o1 = 0.f, o2 = 0.f;
    #pragma unroll
    for (int k = 0; k < 8; k++) { o1 += red1[k][t]; o2 += red2[k][t]; }
    pcat[(size_t)g * 512 + t]       = f2b(o1);
    pcat[(size_t)g * 512 + 256 + t] = f2b(o2);
}

// ---------------- head stage 1 (MFMA): Hf[500 x 768] = relu(pcat @ lin1_W + b1) ----------------
__global__ __launch_bounds__(256)
void head1_mfma(const unsigned short* __restrict__ A,    // [GPAD][512] bf16 (pcat)
                const unsigned short* __restrict__ Wh,   // [768][512] bf16, Wh[n][k]
                const float* __restrict__ b1,
                float* __restrict__ Hf) {                // [GPAD][768] f32
    __shared__ __align__(16) unsigned short Asb[64 * 64];    // 8 KB
    __shared__ __align__(16) unsigned short Bsb[256 * 64];   // 32 KB

    int t = threadIdx.x;
    int wave = t >> 6, lane = t & 63;
    int n0 = blockIdx.x * 256;
    int m0 = blockIdx.y * 64;
    int wc = wave * 64;
    int rsel = lane & 15;
    int kgrp = lane >> 4;
    int cr = lane >> 4;

    float bb[4];
    #pragma unroll
    for (int n = 0; n < 4; n++) bb[n] = b1[n0 + wc + n * 16 + rsel];

    f32x4 acc[4][4];
    #pragma unroll
    for (int m = 0; m < 4; m++)
        #pragma unroll
        for (int n = 0; n < 4; n++)
            acc[m][n] = (f32x4){0.f, 0.f, 0.f, 0.f};

    int arow0 = t >> 3, achk0 = t & 7;
    int arow1 = (256 + t) >> 3, achk1 = t & 7;
    const char* Abase = (const char*)A + (size_t)m0 * 1024;   // row stride 512 bf16 = 1024 B

    for (int ks = 0; ks < 8; ks++) {
        size_t ko = (size_t)ks * 128;   // 64 bf16 per step
        g2l16(Abase + (size_t)arow0 * 1024 + ko + ((achk0 ^ (arow0 & 7)) << 4),
              (char*)Asb + (size_t)t * 16);
        g2l16(Abase + (size_t)arow1 * 1024 + ko + ((achk1 ^ (arow1 & 7)) << 4),
              (char*)Asb + (size_t)(256 + t) * 16);
        #pragma unroll
        for (int i = 0; i < 8; i++) {
            int s = i * 256 + t;
            int brow = s >> 3, bchk = s & 7;
            g2l16((const char*)Wh + (size_t)(n0 + brow) * 1024 + ko + ((bchk ^ (brow & 7)) << 4),
                  (char*)Bsb + (size_t)s * 16);
        }
        __syncthreads();

        #pragma unroll
        for (int ksub = 0; ksub < 2; ksub++) {
            bf16x8 af[4], bfr[4];
            int kchunk = ksub * 4 + kgrp;
            #pragma unroll
            for (int m = 0; m < 4; m++) {
                int row = m * 16 + rsel;
                af[m] = *(const bf16x8*)((const char*)Asb + (size_t)row * 128
                                         + ((kchunk ^ (row & 7)) << 4));
            }
            #pragma unroll
            for (int n = 0; n < 4; n++) {
                int row = wc + n * 16 + rsel;
                bfr[n] = *(const bf16x8*)((const char*)Bsb + (size_t)row * 128
                                          + ((kchunk ^ (row & 7)) << 4));
            }
            #pragma unroll
            for (int m = 0; m < 4; m++)
                #pragma unroll
                for (int n = 0; n < 4; n++)
                    acc[m][n] = __builtin_amdgcn_mfma_f32_16x16x32_bf16(af[m], bfr[n], acc[m][n], 0, 0, 0);
        }
        __syncthreads();
    }

    // epilogue: Hf = relu(acc + b1), f32 store; C/D map col=lane&15, row=(lane>>4)*4+reg
    #pragma unroll
    for (int n = 0; n < 4; n++) {
        int colg = n0 + wc + n * 16 + rsel;
        #pragma unroll
        for (int m = 0; m < 4; m++) {
            int rowb = m0 + m * 16 + cr * 4;
            #pragma unroll
            for (int r = 0; r < 4; r++) {
                int row = rowb + r;
                if (row < N_GRAPHS)
                    Hf[(size_t)row * 768 + colg] = fmaxf(acc[m][n][r] + bb[n], 0.f);
            }
        }
    }
}

// ---------------- head stage 2: GEMV + log_softmax ----------------
__global__ void head2(const float* __restrict__ Hf, const float* __restrict__ W2,
                      const float* __restrict__ b2, float* __restrict__ out) {
    int g = blockIdx.x;
    int lane = threadIdx.x;   // 64
    float part[N_OUT];
    #pragma unroll
    for (int o = 0; o < N_OUT; o++) part[o] = 0.f;
    for (int k = lane; k < 768; k += 64) {
        float hv = Hf[(size_t)g * 768 + k];
        #pragma unroll
        for (int o = 0; o < N_OUT; o++) part[o] += hv * W2[(size_t)k * N_OUT + o];
    }
    #pragma unroll
    for (int o = 0; o < N_OUT; o++) {
        #pragma unroll
        for (int off = 32; off > 0; off >>= 1)
            part[o] += __shfl_down(part[o], off, 64);
    }
    if (lane == 0) {
        float logits[N_OUT];
        float mx = -1e30f;
        #pragma unroll
        for (int o = 0; o < N_OUT; o++) { logits[o] = part[o] + b2[o]; mx = fmaxf(mx, logits[o]); }
        float ssum = 0.f;
        #pragma unroll
        for (int o = 0; o < N_OUT; o++) ssum += expf(logits[o] - mx);
        float lse = logf(ssum);
        #pragma unroll
        for (int o = 0; o < N_OUT; o++)
            out[(size_t)g * N_OUT + o] = logits[o] - mx - lse;
    }
}

extern "C" void kernel_launch(void* const* d_in, const int* in_sizes, int n_in,
                              void* d_out, int out_size, void* d_ws, size_t ws_size,
                              hipStream_t stream) {
    const float* x     = (const float*)d_in[0];
    const int*   ei    = (const int*)d_in[1];
    const int*   batch = (const int*)d_in[2];
    const float* W1a = (const float*)d_in[3];
    const float* b1a = (const float*)d_in[4];
    const float* g1a = (const float*)d_in[5];
    const float* be1a= (const float*)d_in[6];
    const float* m1a = (const float*)d_in[7];
    const float* v1a = (const float*)d_in[8];
    const float* W2a = (const float*)d_in[9];
    const float* b2a = (const float*)d_in[10];
    const float* W1b = (const float*)d_in[11];
    const float* b1b = (const float*)d_in[12];
    const float* g1b = (const float*)d_in[13];
    const float* be1b= (const float*)d_in[14];
    const float* m1b = (const float*)d_in[15];
    const float* v1b = (const float*)d_in[16];
    const float* W2b = (const float*)d_in[17];
    const float* b2b = (const float*)d_in[18];
    const float* lin1_W = (const float*)d_in[19];
    const float* lin1_b = (const float*)d_in[20];
    const float* lin2_W = (const float*)d_in[21];
    const float* lin2_b = (const float*)d_in[22];

    const size_t NBUF = (size_t)MPAD * DIM;
    char* ws = (char*)d_ws;
    unsigned short* agg  = (unsigned short*)ws;            ws += NBUF * 2;
    unsigned short* h1   = (unsigned short*)ws;            ws += NBUF * 2;
    unsigned short* h2   = (unsigned short*)ws;            ws += NBUF * 2;
    unsigned short* x_bf = (unsigned short*)ws;            ws += (size_t)N_NODES * DIM * 2;
    unsigned short* Wt   = (unsigned short*)ws;            ws += 4 * 65536 * 2;
    unsigned short* W1h  = (unsigned short*)ws;            ws += (size_t)768 * 512 * 2;
    float* ss    = (float*)ws;                             ws += 4 * 256 * 4;   // scaleA,shiftA,scaleB,shiftB
    unsigned short* pcat = (unsigned short*)ws;            ws += (size_t)GPAD * 512 * 2;
    float* Hf    = (float*)ws;                             ws += (size_t)GPAD * 768 * 4;
    int* deg     = (int*)ws;                               ws += (size_t)N_NODES * 4;
    int* cursor  = (int*)ws;                               ws += (size_t)N_NODES * 4;
    int* rowptr  = (int*)ws;                               ws += (size_t)(N_NODES + 1) * 4;
    int* bsum    = (int*)ws;                               ws += 64 * 4;
    unsigned short* col = (unsigned short*)ws;             ws += (size_t)N_EDGES * 2;
    int* gstart  = (int*)ws;

    const int* srcE = ei;
    const int* dstE = ei + N_EDGES;

    const int nscan = (N_NODES + SCAN_BS - 1) / SCAN_BS;

    // ---- CSR build (by dst), shared by both layers; sorted for determinism ----
    prep_misc<<<198, 256, 0, stream>>>(deg, batch, gstart);
    hist_dst<<<(N_EDGES + 255) / 256, 256, 0, stream>>>(dstE, deg);
    scan_phase1<<<nscan, SCAN_BS, 0, stream>>>(deg, rowptr, bsum, N_NODES);
    scan_phase2<<<1, 64, 0, stream>>>(bsum, nscan);
    scan_phase3<<<nscan, SCAN_BS, 0, stream>>>(rowptr, cursor, bsum, N_NODES);
    fill_csr<<<(N_EDGES + 255) / 256, 256, 0, stream>>>(srcE, dstE, cursor, col);
    sort_csr<<<(N_NODES + 3) / 4, 256, 0, stream>>>(rowptr, col);

    // ---- precompute ----
    conv_x<<<(N_NODES * DIM / 4 + 255) / 256, 256, 0, stream>>>(
        (const float4*)x, (ushort4*)x_bf, N_NODES * DIM / 4);
    dim3 wss_grid(256, 5);
    conv_wss<<<wss_grid, 256, 0, stream>>>(W1a, W2a, W1b, W2b, Wt,
                                           b1a, g1a, be1a, m1a, v1a,
                                           b1b, g1b, be1b, m1b, v1b, ss);
    conv_w1h<<<768, 256, 0, stream>>>(lin1_W, W1h);

    // ---- layer 1 ----
    gather_bf<<<(N_NODES + 3) / 4, 256, 0, stream>>>(x_bf, col, rowptr, agg);
    fused_mlp<<<MPAD / 64, 256, 0, stream>>>(agg, Wt + 0 * 65536, Wt + 1 * 65536,
                                             ss, ss + 256, b2a, h1, N_NODES);

    // ---- layer 2 ----
    gather_bf<<<(N_NODES + 3) / 4, 256, 0, stream>>>(h1, col, rowptr, agg);
    fused_mlp<<<MPAD / 64, 256, 0, stream>>>(agg, Wt + 2 * 65536, Wt + 3 * 65536,
                                             ss + 512, ss + 768, b2b, h2, N_NODES);

    // ---- pooling + head ----
    pool_seg<<<N_GRAPHS, 256, 0, stream>>>(h1, h2, gstart, pcat);
    dim3 h1grid(3, 8);
    head1_mfma<<<h1grid, 256, 0, stream>>>(pcat, W1h, lin1_b, Hf);
    head2<<<N_GRAPHS, 64, 0, stream>>>(Hf, lin2_W, lin2_b, (float*)d_out);
}